// Round 1
// baseline (804.299 us; speedup 1.0000x reference)
//
#include <hip/hip_runtime.h>
#include <hip/hip_cooperative_groups.h>
#include <cfloat>

namespace cg = cooperative_groups;

#define NN   1024
#define NE   16384
#define D0   128
#define EDIM 16
#define NH1  64
#define NOUT 40
#define KTOP 8
#define NEGINF (-1000000000.0f)
#define MAXDEG 64   // out-deg ~ Poisson(16), gumbel in-deg ~ Poisson(8); P(>64) ~ 1e-20

// ---- workspace layout (bytes); counters zeroed in-kernel (coop) or by memset (fallback) ----
#define OFF_CNTS  0u        // 1024 int (src list counts)
#define OFF_CNTD  4096u     // 1024 int (dst list counts)
#define OFF_SE    8192u     // NE f
#define OFF_A     73728u    // 1024 f
#define OFF_B     77824u    // 1024 f
#define OFF_EM    81920u    // 8192 int
#define OFF_SLOTS 114688u   // 1024*64 int (src lists, fixed stride)
#define OFF_SLOTD 376832u   // 1024*64 int (dst lists, fixed stride)
#define OFF_H     638976u   // 1024*64 f

__device__ __forceinline__ void amx(float& v, int& j, float ov, int oj) {
    if (ov > v || (ov == v && oj < j)) { v = ov; j = oj; }
}

// ============================================================================
// FUSED COOPERATIVE KERNEL: 1024 blocks x 256 threads, 4 grid syncs.
// Phase 0: zero counters (replaces memset dispatch)
// Phase 1: se[e] + per-src edge scatter (blocks 0..63); a,b row dots (64..319)
// Phase 2: per-row masked softmax + gumbel + top-8 (block i = row i),
//          register-resident values, per-wave top-8 (barrier-free) + wave0 merge
// Phase 3: GENConv1 (blocks 0..511, 2 rows each — same body as verified kernel)
// Phase 4: GENConv2 + head (blocks 0..255, 4 rows each)
// __launch_bounds__(256,4): 4 waves/EU -> <=128 VGPR -> 4 blocks/CU -> 1024
// blocks co-resident (required for cooperative launch of grid=1024).
// LDS: union of phase needs = 21.5KB/block -> 86KB/CU at 4 blocks. OK.
// ============================================================================
__global__ __launch_bounds__(256, 4) void fused_kernel(
    const float* __restrict__ x, const float* __restrict__ ea, const float* __restrict__ u,
    const float* __restrict__ mlp_w, const float* __restrict__ mlp_b,
    const float* __restrict__ c1_we, const float* __restrict__ c1_be,
    const float* __restrict__ c1_w1, const float* __restrict__ c1_b1,
    const float* __restrict__ c1_w2, const float* __restrict__ c1_b2,
    const float* __restrict__ c2_we, const float* __restrict__ c2_be,
    const float* __restrict__ c2_w1, const float* __restrict__ c2_b1,
    const float* __restrict__ c2_w2, const float* __restrict__ c2_b2,
    const float* __restrict__ fcw, const float* __restrict__ fcb,
    const int* __restrict__ ei, const int* __restrict__ mask,
    int* __restrict__ cnt_src, int* __restrict__ cntd,
    float* __restrict__ se, float* __restrict__ a, float* __restrict__ b,
    int* __restrict__ em, int* __restrict__ slot_s, int* __restrict__ slotd,
    float* __restrict__ h, float* __restrict__ out)
{
    cg::grid_group grid = cg::this_grid();
    const int bid = blockIdx.x, t = threadIdx.x;
    const int lane = t & 63, wid = t >> 6;

    __shared__ union {
        struct {
            int idmx[NN]; int idmn[NN];
            float wred[8]; float candv[32]; int candj[32]; int selj[KTOP];
        } tk;
        struct {
            int slots[2][MAXDEG]; float eatt[2][MAXDEG * EDIM];
            float arow[2][D0]; float t1s[2][2 * D0];
        } g1;
        struct {
            int slots[4][MAXDEG]; float eatt[4][MAXDEG * EDIM];
            float arow[4][NH1]; float t2s[4][2 * NH1]; float h2s[4][NH1];
        } g2;
    } sh;

    // ---------------- phase 0: zero counters ----------------
    if (t == 0) cnt_src[bid] = 0;
    if (t == 1) cntd[bid] = 0;
    __threadfence();
    grid.sync();

    // ---------------- phase 1: prep ----------------
    if (bid < 64) {
        int e = bid * 256 + t;
        float acc = 0.f;
        #pragma unroll
        for (int k = 0; k < EDIM; k++) acc += ea[e * EDIM + k] * mlp_w[2 * D0 + k];
        se[e] = acc;
        int s = ei[e];
        int p = atomicAdd(&cnt_src[s], 1);
        if (p < MAXDEG) slot_s[s * MAXDEG + p] = e;  // order nondeterministic; consumer is max/min
    } else if (bid < 320) {
        int row = (bid - 64) * 4 + wid;
        const float* xr = x + row * D0;
        float x0 = xr[lane], x1 = xr[64 + lane];
        float sa = x0 * mlp_w[lane]       + x1 * mlp_w[64 + lane];
        float sb = x0 * mlp_w[128 + lane] + x1 * mlp_w[192 + lane];
        for (int s2 = 32; s2; s2 >>= 1) { sa += __shfl_down(sa, s2); sb += __shfl_down(sb, s2); }
        if (lane == 0) { a[row] = sa; b[row] = sb; }
    }
    __threadfence();
    grid.sync();

    // ---------------- phase 2: row softmax + gumbel + top-8 ----------------
    {
        const int i = bid;
        #pragma unroll
        for (int q = 0; q < 4; q++) { int j = t + q * 256; sh.tk.idmx[j] = -1; sh.tk.idmn[j] = 0x7FFFFFFF; }
        __syncthreads();
        int deg = min(cnt_src[i], MAXDEG);
        if (t < deg) {
            int e = slot_s[i * MAXDEG + t];
            int dj = ei[NE + e];
            atomicMax(&sh.tk.idmx[dj], e);
            atomicMin(&sh.tk.idmn[dj], e);
        }
        __syncthreads();

        const float bias = mlp_b[0];
        const float ai = a[i];
        float val[4];
        float lmax = NEGINF;
        #pragma unroll
        for (int q = 0; q < 4; q++) {
            int j = t + q * 256;
            int id = sh.tk.idmx[j];
            float s = (id >= 0) ? (((ai + b[j]) + se[id]) + bias) : NEGINF;
            val[q] = s;
            lmax = fmaxf(lmax, s);
        }
        for (int s = 32; s; s >>= 1) lmax = fmaxf(lmax, __shfl_down(lmax, s));
        if (lane == 0) sh.tk.wred[wid] = lmax;
        __syncthreads();
        float rowmax = fmaxf(fmaxf(sh.tk.wred[0], sh.tk.wred[1]), fmaxf(sh.tk.wred[2], sh.tk.wred[3]));
        bool noedge = (rowmax == NEGINF);

        float lsum = 0.f;
        #pragma unroll
        for (int q = 0; q < 4; q++) {
            float evv;
            if (noedge) evv = 1.0f;
            else { float s = val[q]; evv = (s == NEGINF) ? 0.0f : expf(s - rowmax); }
            val[q] = evv;
            lsum += evv;
        }
        for (int s = 32; s; s >>= 1) lsum += __shfl_down(lsum, s);
        if (lane == 0) sh.tk.wred[4 + wid] = lsum;  // disjoint slots: no extra barrier needed
        __syncthreads();
        float rsum = sh.tk.wred[4] + sh.tk.wred[5] + sh.tk.wred[6] + sh.tk.wred[7];

        const int rowoff = i * NN;
        #pragma unroll
        for (int q = 0; q < 4; q++) {
            int j = t + q * 256;
            float z = val[q] / rsum;
            float uu = u[rowoff + j];
            float g = -logf(-logf(uu + 1e-20f) + 1e-20f);
            val[q] = z + g;
        }

        // per-wave top-8 over this wave's 256 columns — register-resident, no barriers.
        // (any global top-8 element is necessarily in its wave's top-8 under the same
        //  total order (v desc, j asc), so the 32 candidates cover the answer.)
        for (int sel = 0; sel < KTOP; sel++) {
            float bv = -FLT_MAX; int bj = NN;
            #pragma unroll
            for (int q = 0; q < 4; q++) amx(bv, bj, val[q], t + q * 256);
            for (int s = 32; s; s >>= 1) {
                float ov = __shfl_down(bv, s); int oj = __shfl_down(bj, s);
                amx(bv, bj, ov, oj);
            }
            int wjw = __shfl(bj, 0);
            if (lane == 0) { sh.tk.candv[wid * KTOP + sel] = bv; sh.tk.candj[wid * KTOP + sel] = bj; }
            #pragma unroll
            for (int q = 0; q < 4; q++) if (t + q * 256 == wjw) val[q] = -FLT_MAX;
        }
        __syncthreads();

        // wave 0 merges the 32 candidates (all distinct j) into the global top-8
        if (wid == 0) {
            float mv = (lane < 32) ? sh.tk.candv[lane] : -FLT_MAX;
            int   mj = (lane < 32) ? sh.tk.candj[lane] : NN;
            for (int sel = 0; sel < KTOP; sel++) {
                float bv = mv; int bj = mj;
                for (int s = 32; s; s >>= 1) {
                    float ov = __shfl_down(bv, s); int oj = __shfl_down(bj, s);
                    amx(bv, bj, ov, oj);
                }
                int wj = __shfl(bj, 0);
                if (lane == 0) {
                    sh.tk.selj[sel] = wj;
                    int mn = sh.tk.idmn[wj];
                    em[i * KTOP + sel] = (mn == 0x7FFFFFFF) ? 0 : mn;
                }
                if (mj == wj) mv = -FLT_MAX;
            }
        }
        __syncthreads();
        if (t < KTOP) {
            int j = sh.tk.selj[t];
            int n = i * KTOP + t;
            int p = atomicAdd(&cntd[j], 1);
            if (p < MAXDEG) slotd[j * MAXDEG + p] = n;
        }
    }
    __threadfence();
    grid.sync();

    // ---------------- phase 3: GENConv1 (2 rows per block, blocks 0..511) ----------------
    if (bid < 512) {
        const int sub = t >> 7, d = t & 127;
        const int r = bid * 2 + sub;
        const int cnt = min(cntd[r], MAXDEG);
        if (d < cnt) sh.g1.slots[sub][d] = slotd[r * MAXDEG + d];
        __syncthreads();
        if (d == 0) {  // ascending-n order (deterministic)
            for (int p = 1; p < cnt; p++) {
                int v = sh.g1.slots[sub][p]; int q = p - 1;
                while (q >= 0 && sh.g1.slots[sub][q] > v) { sh.g1.slots[sub][q + 1] = sh.g1.slots[sub][q]; q--; }
                sh.g1.slots[sub][q + 1] = v;
            }
        }
        __syncthreads();
        for (int q = d; q < cnt * EDIM; q += 128)
            sh.g1.eatt[sub][q] = ea[em[sh.g1.slots[sub][q >> 4]] * EDIM + (q & 15)];
        __syncthreads();

        float wed[EDIM];
        #pragma unroll
        for (int k = 0; k < EDIM; k++) wed[k] = c1_we[k * D0 + d];
        const float bed = c1_be[d];

        float mxv = -FLT_MAX;
        for (int idx = 0; idx < cnt; idx++) {
            int src = sh.g1.slots[sub][idx] >> 3;
            float ep = bed;
            #pragma unroll
            for (int k = 0; k < EDIM; k++) ep += sh.g1.eatt[sub][idx * EDIM + k] * wed[k];
            float m = fmaxf(x[src * D0 + d] + ep, 0.f) + 1e-7f;
            mxv = fmaxf(mxv, m);
        }
        float den = 0.f, num = 0.f;
        for (int idx = 0; idx < cnt; idx++) {
            int src = sh.g1.slots[sub][idx] >> 3;
            float ep = bed;
            #pragma unroll
            for (int k = 0; k < EDIM; k++) ep += sh.g1.eatt[sub][idx * EDIM + k] * wed[k];
            float m = fmaxf(x[src * D0 + d] + ep, 0.f) + 1e-7f;
            float w = expf(m - mxv);
            den += w; num += w * m;
        }
        float agg = cnt ? num / (den > 0.f ? den : 1.f) : 0.f;
        sh.g1.arow[sub][d] = agg + x[r * D0 + d];
        __syncthreads();

        float acc0 = c1_b1[d], acc1 = c1_b1[d + D0];
        for (int k = 0; k < D0; k++) {
            float av = sh.g1.arow[sub][k];
            acc0 += av * c1_w1[k * 2 * D0 + d];
            acc1 += av * c1_w1[k * 2 * D0 + d + D0];
        }
        sh.g1.t1s[sub][d] = fmaxf(acc0, 0.f);
        sh.g1.t1s[sub][d + D0] = fmaxf(acc1, 0.f);
        __syncthreads();
        if (d < NH1) {
            float acc = c1_b2[d];
            for (int k = 0; k < 2 * D0; k++) acc += sh.g1.t1s[sub][k] * c1_w2[k * NH1 + d];
            h[r * NH1 + d] = fmaxf(acc, 0.f);
        }
    }
    __threadfence();
    grid.sync();

    // ---------------- phase 4: GENConv2 + head (4 rows per block, blocks 0..255) ----------------
    if (bid < 256) {
        const int sub = t >> 6, d = t & 63;
        const int r = bid * 4 + sub;
        const int cnt = min(cntd[r], MAXDEG);
        if (d < cnt) sh.g2.slots[sub][d] = slotd[r * MAXDEG + d];
        __syncthreads();
        if (d == 0) {
            for (int p = 1; p < cnt; p++) {
                int v = sh.g2.slots[sub][p]; int q = p - 1;
                while (q >= 0 && sh.g2.slots[sub][q] > v) { sh.g2.slots[sub][q + 1] = sh.g2.slots[sub][q]; q--; }
                sh.g2.slots[sub][q + 1] = v;
            }
        }
        __syncthreads();
        for (int q = d; q < cnt * EDIM; q += 64)
            sh.g2.eatt[sub][q] = ea[em[sh.g2.slots[sub][q >> 4]] * EDIM + (q & 15)];
        __syncthreads();

        float wed[EDIM];
        #pragma unroll
        for (int k = 0; k < EDIM; k++) wed[k] = c2_we[k * NH1 + d];
        const float bed = c2_be[d];

        float mxv = -FLT_MAX;
        for (int idx = 0; idx < cnt; idx++) {
            int src = sh.g2.slots[sub][idx] >> 3;
            float ep = bed;
            #pragma unroll
            for (int k = 0; k < EDIM; k++) ep += sh.g2.eatt[sub][idx * EDIM + k] * wed[k];
            float m = fmaxf(h[src * NH1 + d] + ep, 0.f) + 1e-7f;
            mxv = fmaxf(mxv, m);
        }
        float den = 0.f, num = 0.f;
        for (int idx = 0; idx < cnt; idx++) {
            int src = sh.g2.slots[sub][idx] >> 3;
            float ep = bed;
            #pragma unroll
            for (int k = 0; k < EDIM; k++) ep += sh.g2.eatt[sub][idx * EDIM + k] * wed[k];
            float m = fmaxf(h[src * NH1 + d] + ep, 0.f) + 1e-7f;
            float w = expf(m - mxv);
            den += w; num += w * m;
        }
        float agg = cnt ? num / (den > 0.f ? den : 1.f) : 0.f;
        sh.g2.arow[sub][d] = agg + h[r * NH1 + d];
        __syncthreads();

        {
            float acc_a = c2_b1[d], acc_b = c2_b1[d + NH1];
            for (int k = 0; k < NH1; k++) {
                float av = sh.g2.arow[sub][k];
                acc_a += av * c2_w1[k * 2 * NH1 + d];
                acc_b += av * c2_w1[k * 2 * NH1 + d + NH1];
            }
            sh.g2.t2s[sub][d] = fmaxf(acc_a, 0.f);
            sh.g2.t2s[sub][d + NH1] = fmaxf(acc_b, 0.f);
        }
        __syncthreads();
        {
            float acc = c2_b2[d];
            for (int k = 0; k < 2 * NH1; k++) acc += sh.g2.t2s[sub][k] * c2_w2[k * NH1 + d];
            sh.g2.h2s[sub][d] = fmaxf(acc, 0.f);
        }
        __syncthreads();
        if (d < NOUT) {
            float acc = fcb[d];
            for (int k = 0; k < NH1; k++) acc += sh.g2.h2s[sub][k] * fcw[k * NOUT + d];
            out[r * NOUT + d] = (mask[r] != 0) ? acc : 0.f;
        }
    }
}

// ============================================================================
// FALLBACK PATH: the verified 4-kernel pipeline (used if cooperative launch
// is rejected, e.g. by graph capture). Identical to the previous best kernel.
// ============================================================================

__global__ __launch_bounds__(256) void prep_kernel(
    const float* __restrict__ x, const float* __restrict__ ea,
    const float* __restrict__ mlp_w, const int* __restrict__ ei,
    float* __restrict__ se, float* __restrict__ a, float* __restrict__ b,
    int* __restrict__ cnt_src, int* __restrict__ slot_src)
{
    const int bid = blockIdx.x, t = threadIdx.x;
    if (bid < 64) {
        int e = bid * 256 + t;
        float acc = 0.f;
        #pragma unroll
        for (int k = 0; k < EDIM; k++) acc += ea[e * EDIM + k] * mlp_w[2 * D0 + k];
        se[e] = acc;
        int s = ei[e];
        int p = atomicAdd(&cnt_src[s], 1);
        if (p < MAXDEG) slot_src[s * MAXDEG + p] = e;
    } else {
        int lane = t & 63, wid = t >> 6;
        int row = (bid - 64) * 4 + wid;
        const float* xr = x + row * D0;
        float x0 = xr[lane], x1 = xr[64 + lane];
        float sa = x0 * mlp_w[lane]       + x1 * mlp_w[64 + lane];
        float sb = x0 * mlp_w[128 + lane] + x1 * mlp_w[192 + lane];
        for (int s2 = 32; s2; s2 >>= 1) { sa += __shfl_down(sa, s2); sb += __shfl_down(sb, s2); }
        if (lane == 0) { a[row] = sa; b[row] = sb; }
    }
}

__global__ __launch_bounds__(256) void row_topk_kernel(
    const float* __restrict__ se, const float* __restrict__ mlp_b,
    const float* __restrict__ a, const float* __restrict__ b,
    const float* __restrict__ u, const int* __restrict__ ei,
    const int* __restrict__ cnt_src, const int* __restrict__ slot_src,
    int* __restrict__ em, int* __restrict__ cntd, int* __restrict__ slotd)
{
    __shared__ float sv[NN];
    __shared__ int   idmx[NN];
    __shared__ int   idmn[NN];
    __shared__ float wred[4];
    __shared__ int   wredj[4];
    __shared__ int   selj[KTOP];
    const int i = blockIdx.x, t = threadIdx.x;
    const int lane = t & 63, wid = t >> 6;
    const int rowoff = i * NN;
    const float bias = mlp_b[0];
    const float ai = a[i];

    #pragma unroll
    for (int q = 0; q < 4; q++) { int j = t + q * 256; idmx[j] = -1; idmn[j] = 0x7FFFFFFF; }
    __syncthreads();
    int deg = min(cnt_src[i], MAXDEG);
    if (t < deg) {
        int e = slot_src[i * MAXDEG + t];
        int dj = ei[NE + e];
        atomicMax(&idmx[dj], e);
        atomicMin(&idmn[dj], e);
    }
    __syncthreads();

    float lmax = NEGINF;
    #pragma unroll
    for (int q = 0; q < 4; q++) {
        int j = t + q * 256;
        int id = idmx[j];
        float s = (id >= 0) ? (((ai + b[j]) + se[id]) + bias) : NEGINF;
        sv[j] = s;
        lmax = fmaxf(lmax, s);
    }
    for (int s = 32; s; s >>= 1) lmax = fmaxf(lmax, __shfl_down(lmax, s));
    if (lane == 0) wred[wid] = lmax;
    __syncthreads();
    float rowmax = fmaxf(fmaxf(wred[0], wred[1]), fmaxf(wred[2], wred[3]));
    bool noedge = (rowmax == NEGINF);
    __syncthreads();

    float lsum = 0.f;
    #pragma unroll
    for (int q = 0; q < 4; q++) {
        int j = t + q * 256;
        float evv;
        if (noedge) evv = 1.0f;
        else { float s = sv[j]; evv = (s == NEGINF) ? 0.0f : expf(s - rowmax); }
        sv[j] = evv;
        lsum += evv;
    }
    for (int s = 32; s; s >>= 1) lsum += __shfl_down(lsum, s);
    if (lane == 0) wred[wid] = lsum;
    __syncthreads();
    float rsum = wred[0] + wred[1] + wred[2] + wred[3];
    __syncthreads();

    #pragma unroll
    for (int q = 0; q < 4; q++) {
        int j = t + q * 256;
        float z = sv[j] / rsum;
        float uu = u[rowoff + j];
        float g = -logf(-logf(uu + 1e-20f) + 1e-20f);
        sv[j] = z + g;
    }
    __syncthreads();

    for (int sel = 0; sel < KTOP; sel++) {
        float bv = -FLT_MAX; int bj = NN;
        #pragma unroll
        for (int q = 0; q < 4; q++) { int j = t + q * 256; amx(bv, bj, sv[j], j); }
        for (int s = 32; s; s >>= 1) {
            float ov = __shfl_down(bv, s); int oj = __shfl_down(bj, s);
            amx(bv, bj, ov, oj);
        }
        if (lane == 0) { wred[wid] = bv; wredj[wid] = bj; }
        __syncthreads();
        if (t == 0) {
            float v = wred[0]; int j = wredj[0];
            amx(v, j, wred[1], wredj[1]);
            amx(v, j, wred[2], wredj[2]);
            amx(v, j, wred[3], wredj[3]);
            selj[sel] = j;
            int mn = idmn[j];
            em[i * KTOP + sel] = (mn == 0x7FFFFFFF) ? 0 : mn;
            sv[j] = -FLT_MAX;
        }
        __syncthreads();
    }
    if (t < KTOP) {
        int j = selj[t];
        int n = i * KTOP + t;
        int p = atomicAdd(&cntd[j], 1);
        if (p < MAXDEG) slotd[j * MAXDEG + p] = n;
    }
}

__global__ __launch_bounds__(256) void genconv1_kernel(
    const float* __restrict__ x, const float* __restrict__ ea,
    const float* __restrict__ we_g, const float* __restrict__ be,
    const float* __restrict__ w1, const float* __restrict__ b1,
    const float* __restrict__ w2, const float* __restrict__ b2,
    const int* __restrict__ cntd, const int* __restrict__ slotd,
    const int* __restrict__ em, float* __restrict__ h)
{
    __shared__ int   slots[2][MAXDEG];
    __shared__ float eatt[2][MAXDEG * EDIM];
    __shared__ float arow[2][D0];
    __shared__ float t1s[2][2 * D0];
    const int t = threadIdx.x, sub = t >> 7, d = t & 127;
    const int r = blockIdx.x * 2 + sub;
    const int cnt = min(cntd[r], MAXDEG);
    if (d < cnt) slots[sub][d] = slotd[r * MAXDEG + d];
    __syncthreads();
    if (d == 0) {
        for (int p = 1; p < cnt; p++) {
            int v = slots[sub][p]; int q = p - 1;
            while (q >= 0 && slots[sub][q] > v) { slots[sub][q + 1] = slots[sub][q]; q--; }
            slots[sub][q + 1] = v;
        }
    }
    __syncthreads();
    for (int q = d; q < cnt * EDIM; q += 128)
        eatt[sub][q] = ea[em[slots[sub][q >> 4]] * EDIM + (q & 15)];
    __syncthreads();

    float wed[EDIM];
    #pragma unroll
    for (int k = 0; k < EDIM; k++) wed[k] = we_g[k * D0 + d];
    const float bed = be[d];

    float mxv = -FLT_MAX;
    for (int idx = 0; idx < cnt; idx++) {
        int src = slots[sub][idx] >> 3;
        float ep = bed;
        #pragma unroll
        for (int k = 0; k < EDIM; k++) ep += eatt[sub][idx * EDIM + k] * wed[k];
        float m = fmaxf(x[src * D0 + d] + ep, 0.f) + 1e-7f;
        mxv = fmaxf(mxv, m);
    }
    float den = 0.f, num = 0.f;
    for (int idx = 0; idx < cnt; idx++) {
        int src = slots[sub][idx] >> 3;
        float ep = bed;
        #pragma unroll
        for (int k = 0; k < EDIM; k++) ep += eatt[sub][idx * EDIM + k] * wed[k];
        float m = fmaxf(x[src * D0 + d] + ep, 0.f) + 1e-7f;
        float w = expf(m - mxv);
        den += w; num += w * m;
    }
    float agg = cnt ? num / (den > 0.f ? den : 1.f) : 0.f;
    arow[sub][d] = agg + x[r * D0 + d];
    __syncthreads();

    float acc0 = b1[d], acc1 = b1[d + D0];
    for (int k = 0; k < D0; k++) {
        float av = arow[sub][k];
        acc0 += av * w1[k * 2 * D0 + d];
        acc1 += av * w1[k * 2 * D0 + d + D0];
    }
    t1s[sub][d] = fmaxf(acc0, 0.f);
    t1s[sub][d + D0] = fmaxf(acc1, 0.f);
    __syncthreads();
    if (d < NH1) {
        float acc = b2[d];
        for (int k = 0; k < 2 * D0; k++) acc += t1s[sub][k] * w2[k * NH1 + d];
        h[r * NH1 + d] = fmaxf(acc, 0.f);
    }
}

__global__ __launch_bounds__(256) void genconv2_kernel(
    const float* __restrict__ h, const float* __restrict__ ea,
    const float* __restrict__ we_g, const float* __restrict__ be,
    const float* __restrict__ w1, const float* __restrict__ b1,
    const float* __restrict__ w2, const float* __restrict__ b2,
    const float* __restrict__ fcw, const float* __restrict__ fcb,
    const int* __restrict__ cntd, const int* __restrict__ slotd,
    const int* __restrict__ em, const int* __restrict__ mask,
    float* __restrict__ out)
{
    __shared__ int   slots[4][MAXDEG];
    __shared__ float eatt[4][MAXDEG * EDIM];
    __shared__ float arow[4][NH1];
    __shared__ float t2s[4][2 * NH1];
    __shared__ float h2s[4][NH1];
    const int t = threadIdx.x, sub = t >> 6, d = t & 63;
    const int r = blockIdx.x * 4 + sub;
    const int cnt = min(cntd[r], MAXDEG);
    if (d < cnt) slots[sub][d] = slotd[r * MAXDEG + d];
    __syncthreads();
    if (d == 0) {
        for (int p = 1; p < cnt; p++) {
            int v = slots[sub][p]; int q = p - 1;
            while (q >= 0 && slots[sub][q] > v) { slots[sub][q + 1] = slots[sub][q]; q--; }
            slots[sub][q + 1] = v;
        }
    }
    __syncthreads();
    for (int q = d; q < cnt * EDIM; q += 64)
        eatt[sub][q] = ea[em[slots[sub][q >> 4]] * EDIM + (q & 15)];
    __syncthreads();

    float wed[EDIM];
    #pragma unroll
    for (int k = 0; k < EDIM; k++) wed[k] = we_g[k * NH1 + d];
    const float bed = be[d];

    float mxv = -FLT_MAX;
    for (int idx = 0; idx < cnt; idx++) {
        int src = slots[sub][idx] >> 3;
        float ep = bed;
        #pragma unroll
        for (int k = 0; k < EDIM; k++) ep += eatt[sub][idx * EDIM + k] * wed[k];
        float m = fmaxf(h[src * NH1 + d] + ep, 0.f) + 1e-7f;
        mxv = fmaxf(mxv, m);
    }
    float den = 0.f, num = 0.f;
    for (int idx = 0; idx < cnt; idx++) {
        int src = slots[sub][idx] >> 3;
        float ep = bed;
        #pragma unroll
        for (int k = 0; k < EDIM; k++) ep += eatt[sub][idx * EDIM + k] * wed[k];
        float m = fmaxf(h[src * NH1 + d] + ep, 0.f) + 1e-7f;
        float w = expf(m - mxv);
        den += w; num += w * m;
    }
    float agg = cnt ? num / (den > 0.f ? den : 1.f) : 0.f;
    arow[sub][d] = agg + h[r * NH1 + d];
    __syncthreads();

    {
        float acc_a = b1[d], acc_b = b1[d + NH1];
        for (int k = 0; k < NH1; k++) {
            float av = arow[sub][k];
            acc_a += av * w1[k * 2 * NH1 + d];
            acc_b += av * w1[k * 2 * NH1 + d + NH1];
        }
        t2s[sub][d] = fmaxf(acc_a, 0.f);
        t2s[sub][d + NH1] = fmaxf(acc_b, 0.f);
    }
    __syncthreads();
    {
        float acc = b2[d];
        for (int k = 0; k < 2 * NH1; k++) acc += t2s[sub][k] * w2[k * NH1 + d];
        h2s[sub][d] = fmaxf(acc, 0.f);
    }
    __syncthreads();
    if (d < NOUT) {
        float acc = fcb[d];
        for (int k = 0; k < NH1; k++) acc += h2s[sub][k] * fcw[k * NOUT + d];
        out[r * NOUT + d] = (mask[r] != 0) ? acc : 0.f;
    }
}

extern "C" void kernel_launch(void* const* d_in, const int* in_sizes, int n_in,
                              void* d_out, int out_size, void* d_ws, size_t ws_size,
                              hipStream_t stream) {
    const float* x      = (const float*)d_in[0];
    const float* ea     = (const float*)d_in[1];
    const float* u      = (const float*)d_in[2];
    const float* mlp_w  = (const float*)d_in[3];
    const float* mlp_b  = (const float*)d_in[4];
    const float* c1_we  = (const float*)d_in[5];
    const float* c1_be  = (const float*)d_in[6];
    const float* c1_w1  = (const float*)d_in[7];
    const float* c1_b1  = (const float*)d_in[8];
    const float* c1_w2  = (const float*)d_in[9];
    const float* c1_b2  = (const float*)d_in[10];
    const float* c2_we  = (const float*)d_in[11];
    const float* c2_be  = (const float*)d_in[12];
    const float* c2_w1  = (const float*)d_in[13];
    const float* c2_b1  = (const float*)d_in[14];
    const float* c2_w2  = (const float*)d_in[15];
    const float* c2_b2  = (const float*)d_in[16];
    const float* fc_w   = (const float*)d_in[17];
    const float* fc_b   = (const float*)d_in[18];
    const int*   ei     = (const int*)d_in[20];
    const int*   mask   = (const int*)d_in[21];

    char* ws = (char*)d_ws;
    int*   cnt_src = (int*)(ws + OFF_CNTS);
    int*   cntd    = (int*)(ws + OFF_CNTD);
    float* se      = (float*)(ws + OFF_SE);
    float* a       = (float*)(ws + OFF_A);
    float* b       = (float*)(ws + OFF_B);
    int*   em      = (int*)(ws + OFF_EM);
    int*   slot_s  = (int*)(ws + OFF_SLOTS);
    int*   slotd   = (int*)(ws + OFF_SLOTD);
    float* h       = (float*)(ws + OFF_H);
    float* out     = (float*)d_out;

    // Single cooperative dispatch: phase-0 zeroes counters (replaces memset),
    // 4 grid.sync()s replace 4 dispatch boundaries.
    void* kargs[] = {
        (void*)&x, (void*)&ea, (void*)&u, (void*)&mlp_w, (void*)&mlp_b,
        (void*)&c1_we, (void*)&c1_be, (void*)&c1_w1, (void*)&c1_b1, (void*)&c1_w2, (void*)&c1_b2,
        (void*)&c2_we, (void*)&c2_be, (void*)&c2_w1, (void*)&c2_b1, (void*)&c2_w2, (void*)&c2_b2,
        (void*)&fc_w, (void*)&fc_b, (void*)&ei, (void*)&mask,
        (void*)&cnt_src, (void*)&cntd, (void*)&se, (void*)&a, (void*)&b,
        (void*)&em, (void*)&slot_s, (void*)&slotd, (void*)&h, (void*)&out
    };
    hipError_t err = hipLaunchCooperativeKernel(
        reinterpret_cast<const void*>(&fused_kernel),
        dim3(NN), dim3(256), kargs, 0u, stream);

    if (err != hipSuccess) {
        // Fallback: verified 4-kernel pipeline.
        (void)hipGetLastError();  // clear error state
        hipMemsetAsync(ws + OFF_CNTS, 0, 8192, stream);  // cnt_src + cntd
        prep_kernel<<<320, 256, 0, stream>>>(x, ea, mlp_w, ei, se, a, b, cnt_src, slot_s);
        row_topk_kernel<<<NN, 256, 0, stream>>>(se, mlp_b, a, b, u, ei, cnt_src, slot_s,
                                                em, cntd, slotd);
        genconv1_kernel<<<NN / 2, 256, 0, stream>>>(x, ea, c1_we, c1_be, c1_w1, c1_b1, c1_w2, c1_b2,
                                                    cntd, slotd, em, h);
        genconv2_kernel<<<NN / 4, 256, 0, stream>>>(h, ea, c2_we, c2_be, c2_w1, c2_b1, c2_w2, c2_b2,
                                                    fc_w, fc_b, cntd, slotd, em, mask, out);
    }
}

// Round 2
// 180.356 us; speedup vs baseline: 4.4595x; 4.4595x over previous
//
#include <hip/hip_runtime.h>
#include <cfloat>

#define NN   1024
#define NE   16384
#define D0   128
#define EDIM 16
#define NH1  64
#define NOUT 40
#define KTOP 8
#define NEGINF (-1000000000.0f)
#define MAXDEG 64   // in-deg of selected graph ~ Poisson(8); P(>64) negligible
#define PMAX   64   // distinct-dst count per src row ~ Poisson(16); P(>64) negligible

// ---- workspace layout (bytes); everything written-before-read, no memset ----
#define OFF_EM  0u        // 8192 int  (edge id per selection)
#define OFF_ND  32768u    // 8192 int  (new_dst per selection)
#define OFF_H   65536u    // 1024*64 f (GENConv1 output)

__device__ __forceinline__ void amx(float& v, int& j, float ov, int oj) {
    if (ov > v || (ov == v && oj < j)) { v = ov; j = oj; }
}

// ============================================================================
// Kernel 1: per-row score + gumbel + top-8.  256 blocks x 256 threads.
// Block handles 4 rows (one wave per row). No prep kernel needed:
//  - edge scan (int4, L2-resident) builds idmx/idmn for the block's rows
//  - b[j] / se computed ONLY for matched columns (wave-cooperative dots);
//    unmatched columns are NEGINF before softmax, 0 after (gumbel added to all)
//  - softmax + gumbel + top-8 fully register/shuffle-resident, no barriers
// ============================================================================
__global__ __launch_bounds__(256) void topk_kernel(
    const float* __restrict__ x, const float* __restrict__ ea,
    const float* __restrict__ u, const float* __restrict__ mlp_w,
    const float* __restrict__ mlp_b, const int* __restrict__ ei,
    int* __restrict__ nd, int* __restrict__ em)
{
    __shared__ int idmx[4 * NN];       // 16KB: max edge id per (row,dst), -1 = none
    __shared__ int idmn[4 * NN];       // 16KB: min edge id per (row,dst)
    __shared__ int plj[4 * PMAX];      // matched column list per row
    __shared__ int ple[4 * PMAX];      // matched edge (max id) per row
    __shared__ int np[4];
    const int t = threadIdx.x, lane = t & 63, w = t >> 6;
    const int r0 = blockIdx.x * 4;

    #pragma unroll
    for (int q = 0; q < 16; q++) { idmx[t + q * 256] = -1; idmn[t + q * 256] = 0x7FFFFFFF; }
    if (t < 4) np[t] = 0;
    __syncthreads();

    // ---- edge scan: find edges with src in [r0, r0+4) ----
    const int4* src4 = (const int4*)ei;
    #pragma unroll
    for (int q = 0; q < 16; q++) {
        int idx4 = t + q * 256;
        int4 v = src4[idx4];
        int e0 = idx4 * 4;
        #pragma unroll
        for (int c = 0; c < 4; c++) {
            int s = (c == 0) ? v.x : (c == 1) ? v.y : (c == 2) ? v.z : v.w;
            unsigned rr = (unsigned)(s - r0);
            if (rr < 4u) {
                int e = e0 + c;
                int d = ei[NE + e];
                atomicMax(&idmx[rr * NN + d], e);
                atomicMin(&idmn[rr * NN + d], e);
            }
        }
    }
    __syncthreads();

    // ---- compact matched (row, col) pairs ----
    #pragma unroll
    for (int q = 0; q < 16; q++) {
        int idx = t + q * 256;
        int e = idmx[idx];
        if (e >= 0) {
            int row = idx >> 10;
            int p = atomicAdd(&np[row], 1);
            if (p < PMAX) { plj[row * PMAX + p] = idx & 1023; ple[row * PMAX + p] = e; }
        }
    }
    __syncthreads();

    // ================= per-wave: row r = r0 + w, no barriers below =================
    const int r = r0 + w;

    // a_r = x[r]·w_node (wave-cooperative) ; fold in bias
    float part = x[r * D0 + lane] * mlp_w[lane] + x[r * D0 + 64 + lane] * mlp_w[64 + lane];
    for (int s2 = 32; s2; s2 >>= 1) part += __shfl_down(part, s2);
    const float arb = __shfl(part, 0) + mlp_b[0];

    // scores: val[q] holds column j = q*64 + lane
    float val[16];
    #pragma unroll
    for (int q = 0; q < 16; q++) val[q] = NEGINF;

    const int npw = min(np[w], PMAX);
    for (int p = 0; p < npw; p++) {
        int j = plj[w * PMAX + p], e = ple[w * PMAX + p];   // wave-uniform (LDS broadcast)
        // b_j = x[j]·w_nb ; se = ea[e]·w_e — one fused wave reduction
        float pp = x[j * D0 + lane] * mlp_w[128 + lane]
                 + x[j * D0 + 64 + lane] * mlp_w[192 + lane];
        if (lane < 16) pp += ea[e * EDIM + lane] * mlp_w[256 + lane];
        for (int s2 = 32; s2; s2 >>= 1) pp += __shfl_down(pp, s2);
        float sc = __shfl(pp, 0) + arb;
        #pragma unroll
        for (int q = 0; q < 16; q++)                 // static index (no scratch)
            if (q == (j >> 6) && lane == (j & 63)) val[q] = sc;
    }

    // row max
    float lm = NEGINF;
    #pragma unroll
    for (int q = 0; q < 16; q++) lm = fmaxf(lm, val[q]);
    for (int s2 = 32; s2; s2 >>= 1) lm = fmaxf(lm, __shfl_down(lm, s2));
    const float rowmax = __shfl(lm, 0);
    const bool noedge = (rowmax == NEGINF);

    // exp + row sum (unmatched -> 0; no-edge row -> uniform, matches reference)
    float ls = 0.f;
    #pragma unroll
    for (int q = 0; q < 16; q++) {
        float ev = noedge ? 1.0f : ((val[q] == NEGINF) ? 0.0f : expf(val[q] - rowmax));
        val[q] = ev; ls += ev;
    }
    for (int s2 = 32; s2; s2 >>= 1) ls += __shfl_down(ls, s2);
    const float rsum = __shfl(ls, 0);

    // gumbel: val = z + g (top-k of softmax((z+g)/T) == top-k of z+g, softmax monotone)
    const float* ur = u + r * NN;
    #pragma unroll
    for (int q = 0; q < 16; q++) {
        float uu = ur[q * 64 + lane];
        float g = -logf(-logf(uu + 1e-20f) + 1e-20f);
        val[q] = val[q] / rsum + g;
    }

    // top-8 (v desc, j asc tie-break = jax.lax.top_k)
    for (int sel = 0; sel < KTOP; sel++) {
        float bv = -FLT_MAX; int bj = NN;
        #pragma unroll
        for (int q = 0; q < 16; q++) amx(bv, bj, val[q], q * 64 + lane);
        for (int s2 = 32; s2; s2 >>= 1) {
            float ov = __shfl_down(bv, s2); int oj = __shfl_down(bj, s2);
            amx(bv, bj, ov, oj);
        }
        int wj = __shfl(bj, 0);
        if (lane == 0) {
            int mn = idmn[w * NN + wj];
            em[r * KTOP + sel] = (mn == 0x7FFFFFFF) ? 0 : mn;  // no edge -> argmax(all-false)=0
            nd[r * KTOP + sel] = wj;
        }
        #pragma unroll
        for (int q = 0; q < 16; q++)                 // static index (no scratch)
            if (q == (wj >> 6) && lane == (wj & 63)) val[q] = -FLT_MAX;
    }
}

// ============================================================================
// Kernel 2: GENConv1 fused. 512 blocks, 2 dst rows per block (d = t&127).
// Incoming list built by scanning nd[8192] (L2-broadcast), sorted for determinism.
// ============================================================================
__global__ __launch_bounds__(256) void genconv1_kernel(
    const float* __restrict__ x, const float* __restrict__ ea,
    const float* __restrict__ we_g, const float* __restrict__ be,
    const float* __restrict__ w1, const float* __restrict__ b1,
    const float* __restrict__ w2, const float* __restrict__ b2,
    const int* __restrict__ nd, const int* __restrict__ em,
    float* __restrict__ h)
{
    __shared__ int   slots[2][MAXDEG];
    __shared__ float eatt[2][MAXDEG * EDIM];
    __shared__ float arow[2][D0];
    __shared__ float t1s[2][2 * D0];
    __shared__ int   cnts[2];
    const int t = threadIdx.x, sub = t >> 7, d = t & 127;
    const int r0 = blockIdx.x * 2;
    const int r = r0 + sub;
    if (t < 2) cnts[t] = 0;
    __syncthreads();

    // scan all 8192 selections for matches to this block's 2 rows
    const int4* nd4 = (const int4*)nd;
    #pragma unroll
    for (int q = 0; q < 8; q++) {
        int idx4 = t + q * 256;
        int4 v = nd4[idx4];
        int n0 = idx4 * 4;
        #pragma unroll
        for (int c = 0; c < 4; c++) {
            int dj = (c == 0) ? v.x : (c == 1) ? v.y : (c == 2) ? v.z : v.w;
            unsigned rr = (unsigned)(dj - r0);
            if (rr < 2u) {
                int p = atomicAdd(&cnts[rr], 1);
                if (p < MAXDEG) slots[rr][p] = n0 + c;
            }
        }
    }
    __syncthreads();
    const int cnt = min(cnts[sub], MAXDEG);
    if (d == 0) {  // ascending-n order (deterministic)
        for (int p = 1; p < cnt; p++) {
            int v = slots[sub][p]; int q = p - 1;
            while (q >= 0 && slots[sub][q] > v) { slots[sub][q + 1] = slots[sub][q]; q--; }
            slots[sub][q + 1] = v;
        }
    }
    __syncthreads();
    for (int q = d; q < cnt * EDIM; q += 128)
        eatt[sub][q] = ea[em[slots[sub][q >> 4]] * EDIM + (q & 15)];
    __syncthreads();

    float wed[EDIM];
    #pragma unroll
    for (int k = 0; k < EDIM; k++) wed[k] = we_g[k * D0 + d];
    const float bed = be[d];

    float mxv = -FLT_MAX;
    for (int idx = 0; idx < cnt; idx++) {
        int src = slots[sub][idx] >> 3;
        float ep = bed;
        #pragma unroll
        for (int k = 0; k < EDIM; k++) ep += eatt[sub][idx * EDIM + k] * wed[k];
        float m = fmaxf(x[src * D0 + d] + ep, 0.f) + 1e-7f;
        mxv = fmaxf(mxv, m);
    }
    float den = 0.f, num = 0.f;
    for (int idx = 0; idx < cnt; idx++) {
        int src = slots[sub][idx] >> 3;
        float ep = bed;
        #pragma unroll
        for (int k = 0; k < EDIM; k++) ep += eatt[sub][idx * EDIM + k] * wed[k];
        float m = fmaxf(x[src * D0 + d] + ep, 0.f) + 1e-7f;
        float w = expf(m - mxv);
        den += w; num += w * m;
    }
    float agg = cnt ? num / (den > 0.f ? den : 1.f) : 0.f;
    arow[sub][d] = agg + x[r * D0 + d];
    __syncthreads();

    float acc0 = b1[d], acc1 = b1[d + D0];
    for (int k = 0; k < D0; k++) {
        float av = arow[sub][k];
        acc0 += av * w1[k * 2 * D0 + d];
        acc1 += av * w1[k * 2 * D0 + d + D0];
    }
    t1s[sub][d] = fmaxf(acc0, 0.f);
    t1s[sub][d + D0] = fmaxf(acc1, 0.f);
    __syncthreads();
    if (d < NH1) {
        float acc = b2[d];
        for (int k = 0; k < 2 * D0; k++) acc += t1s[sub][k] * w2[k * NH1 + d];
        h[r * NH1 + d] = fmaxf(acc, 0.f);
    }
}

// ============================================================================
// Kernel 3: GENConv2 + head. 256 blocks, 4 dst rows per block (d = t&63).
// ============================================================================
__global__ __launch_bounds__(256) void genconv2_kernel(
    const float* __restrict__ h, const float* __restrict__ ea,
    const float* __restrict__ we_g, const float* __restrict__ be,
    const float* __restrict__ w1, const float* __restrict__ b1,
    const float* __restrict__ w2, const float* __restrict__ b2,
    const float* __restrict__ fcw, const float* __restrict__ fcb,
    const int* __restrict__ nd, const int* __restrict__ em,
    const int* __restrict__ mask, float* __restrict__ out)
{
    __shared__ int   slots[4][MAXDEG];
    __shared__ float eatt[4][MAXDEG * EDIM];
    __shared__ float arow[4][NH1];
    __shared__ float t2s[4][2 * NH1];
    __shared__ float h2s[4][NH1];
    __shared__ int   cnts[4];
    const int t = threadIdx.x, sub = t >> 6, d = t & 63;
    const int r0 = blockIdx.x * 4;
    const int r = r0 + sub;
    if (t < 4) cnts[t] = 0;
    __syncthreads();

    const int4* nd4 = (const int4*)nd;
    #pragma unroll
    for (int q = 0; q < 8; q++) {
        int idx4 = t + q * 256;
        int4 v = nd4[idx4];
        int n0 = idx4 * 4;
        #pragma unroll
        for (int c = 0; c < 4; c++) {
            int dj = (c == 0) ? v.x : (c == 1) ? v.y : (c == 2) ? v.z : v.w;
            unsigned rr = (unsigned)(dj - r0);
            if (rr < 4u) {
                int p = atomicAdd(&cnts[rr], 1);
                if (p < MAXDEG) slots[rr][p] = n0 + c;
            }
        }
    }
    __syncthreads();
    const int cnt = min(cnts[sub], MAXDEG);
    if (d == 0) {
        for (int p = 1; p < cnt; p++) {
            int v = slots[sub][p]; int q = p - 1;
            while (q >= 0 && slots[sub][q] > v) { slots[sub][q + 1] = slots[sub][q]; q--; }
            slots[sub][q + 1] = v;
        }
    }
    __syncthreads();
    for (int q = d; q < cnt * EDIM; q += 64)
        eatt[sub][q] = ea[em[slots[sub][q >> 4]] * EDIM + (q & 15)];
    __syncthreads();

    float wed[EDIM];
    #pragma unroll
    for (int k = 0; k < EDIM; k++) wed[k] = we_g[k * NH1 + d];
    const float bed = be[d];

    float mxv = -FLT_MAX;
    for (int idx = 0; idx < cnt; idx++) {
        int src = slots[sub][idx] >> 3;
        float ep = bed;
        #pragma unroll
        for (int k = 0; k < EDIM; k++) ep += eatt[sub][idx * EDIM + k] * wed[k];
        float m = fmaxf(h[src * NH1 + d] + ep, 0.f) + 1e-7f;
        mxv = fmaxf(mxv, m);
    }
    float den = 0.f, num = 0.f;
    for (int idx = 0; idx < cnt; idx++) {
        int src = slots[sub][idx] >> 3;
        float ep = bed;
        #pragma unroll
        for (int k = 0; k < EDIM; k++) ep += eatt[sub][idx * EDIM + k] * wed[k];
        float m = fmaxf(h[src * NH1 + d] + ep, 0.f) + 1e-7f;
        float w = expf(m - mxv);
        den += w; num += w * m;
    }
    float agg = cnt ? num / (den > 0.f ? den : 1.f) : 0.f;
    arow[sub][d] = agg + h[r * NH1 + d];
    __syncthreads();

    {
        float acc_a = b1[d], acc_b = b1[d + NH1];
        for (int k = 0; k < NH1; k++) {
            float av = arow[sub][k];
            acc_a += av * w1[k * 2 * NH1 + d];
            acc_b += av * w1[k * 2 * NH1 + d + NH1];
        }
        t2s[sub][d] = fmaxf(acc_a, 0.f);
        t2s[sub][d + NH1] = fmaxf(acc_b, 0.f);
    }
    __syncthreads();
    {
        float acc = b2[d];
        for (int k = 0; k < 2 * NH1; k++) acc += t2s[sub][k] * w2[k * NH1 + d];
        h2s[sub][d] = fmaxf(acc, 0.f);
    }
    __syncthreads();
    if (d < NOUT) {
        float acc = fcb[d];
        for (int k = 0; k < NH1; k++) acc += h2s[sub][k] * fcw[k * NOUT + d];
        out[r * NOUT + d] = (mask[r] != 0) ? acc : 0.f;
    }
}

extern "C" void kernel_launch(void* const* d_in, const int* in_sizes, int n_in,
                              void* d_out, int out_size, void* d_ws, size_t ws_size,
                              hipStream_t stream) {
    const float* x      = (const float*)d_in[0];
    const float* ea     = (const float*)d_in[1];
    const float* u      = (const float*)d_in[2];
    const float* mlp_w  = (const float*)d_in[3];
    const float* mlp_b  = (const float*)d_in[4];
    const float* c1_we  = (const float*)d_in[5];
    const float* c1_be  = (const float*)d_in[6];
    const float* c1_w1  = (const float*)d_in[7];
    const float* c1_b1  = (const float*)d_in[8];
    const float* c1_w2  = (const float*)d_in[9];
    const float* c1_b2  = (const float*)d_in[10];
    const float* c2_we  = (const float*)d_in[11];
    const float* c2_be  = (const float*)d_in[12];
    const float* c2_w1  = (const float*)d_in[13];
    const float* c2_b1  = (const float*)d_in[14];
    const float* c2_w2  = (const float*)d_in[15];
    const float* c2_b2  = (const float*)d_in[16];
    const float* fc_w   = (const float*)d_in[17];
    const float* fc_b   = (const float*)d_in[18];
    const int*   ei     = (const int*)d_in[20];
    const int*   mask   = (const int*)d_in[21];

    char* ws = (char*)d_ws;
    int*   em = (int*)(ws + OFF_EM);
    int*   nd = (int*)(ws + OFF_ND);
    float* h  = (float*)(ws + OFF_H);
    float* out = (float*)d_out;

    // 3 dispatches, no memset, no global atomics, no device barriers.
    topk_kernel<<<NN / 4, 256, 0, stream>>>(x, ea, u, mlp_w, mlp_b, ei, nd, em);
    genconv1_kernel<<<NN / 2, 256, 0, stream>>>(x, ea, c1_we, c1_be, c1_w1, c1_b1, c1_w2, c1_b2,
                                                nd, em, h);
    genconv2_kernel<<<NN / 4, 256, 0, stream>>>(h, ea, c2_we, c2_be, c2_w1, c2_b1, c2_w2, c2_b2,
                                                fc_w, fc_b, nd, em, mask, out);
}

// Round 3
// 161.980 us; speedup vs baseline: 4.9654x; 1.1135x over previous
//
#include <hip/hip_runtime.h>
#include <cfloat>

#define NN   1024
#define NE   16384
#define D0   128
#define EDIM 16
#define NH1  64
#define NOUT 40
#define KTOP 8
#define NEGINF (-1000000000.0f)
#define MAXDEG 64   // in-deg of selected graph ~ Poisson(8); P(>64) negligible
#define PMAX   64   // distinct-dst count per src row ~ Poisson(16); P(>64) negligible

// ---- workspace layout (bytes); everything written-before-read, no memset ----
#define OFF_EM  0u        // 8192 int  (edge id per selection)
#define OFF_ND  32768u    // 8192 int  (new_dst per selection)
#define OFF_H   65536u    // 1024*64 f (GENConv1 output)

__device__ __forceinline__ void amx(float& v, int& j, float ov, int oj) {
    if (ov > v || (ov == v && oj < j)) { v = ov; j = oj; }
}

// ============================================================================
// Kernel 1: per-row score + gumbel + top-8.  1024 blocks x 256 threads
// (one block per row: 4 blocks/CU -> 16 waves/CU for latency hiding).
//  - edge scan: src as int4 (dst scalar only on match) -> idmx/idmn in LDS
//  - matched columns compacted; the ~16 score dots split ACROSS the 4 waves
//    (serial depth ~4 instead of 16), wave-cooperative 128+16 fused dot each
//  - softmax + gumbel in registers; per-wave reg top-8 + wave0 merge
//    (verified logic from the round-1 fused kernel)
// ============================================================================
__global__ __launch_bounds__(256) void topk_kernel(
    const float* __restrict__ x, const float* __restrict__ ea,
    const float* __restrict__ u, const float* __restrict__ mlp_w,
    const float* __restrict__ mlp_b, const int* __restrict__ ei,
    int* __restrict__ nd, int* __restrict__ em)
{
    __shared__ int   idmx[NN];      // max edge id per dst, -1 = none
    __shared__ int   idmn[NN];      // min edge id per dst
    __shared__ float sv[NN];        // scores (NEGINF = unmatched)
    __shared__ int   plj[PMAX];     // matched column list
    __shared__ int   ple[PMAX];     // matched edge (max id)
    __shared__ int   np;
    __shared__ float wred[8];
    __shared__ float candv[32];
    __shared__ int   candj[32];
    const int i = blockIdx.x, t = threadIdx.x;
    const int lane = t & 63, w = t >> 6;

    #pragma unroll
    for (int q = 0; q < 4; q++) {
        int j = t + q * 256;
        idmx[j] = -1; idmn[j] = 0x7FFFFFFF; sv[j] = NEGINF;
    }
    if (t == 0) np = 0;
    __syncthreads();

    // ---- edge scan: src int4; dst fetched scalar only on match (~16/16384) ----
    const int4* s4 = (const int4*)ei;
    #pragma unroll
    for (int q = 0; q < 16; q++) {
        int idx4 = t + q * 256;
        int4 sv4 = s4[idx4];
        int e0 = idx4 * 4;
        if (sv4.x == i) { int dj = ei[NE + e0 + 0]; atomicMax(&idmx[dj], e0 + 0); atomicMin(&idmn[dj], e0 + 0); }
        if (sv4.y == i) { int dj = ei[NE + e0 + 1]; atomicMax(&idmx[dj], e0 + 1); atomicMin(&idmn[dj], e0 + 1); }
        if (sv4.z == i) { int dj = ei[NE + e0 + 2]; atomicMax(&idmx[dj], e0 + 2); atomicMin(&idmn[dj], e0 + 2); }
        if (sv4.w == i) { int dj = ei[NE + e0 + 3]; atomicMax(&idmx[dj], e0 + 3); atomicMin(&idmn[dj], e0 + 3); }
    }
    __syncthreads();

    // ---- compact matched columns ----
    #pragma unroll
    for (int q = 0; q < 4; q++) {
        int j = t + q * 256;
        int e = idmx[j];
        if (e >= 0) {
            int p = atomicAdd(&np, 1);
            if (p < PMAX) { plj[p] = j; ple[p] = e; }
        }
    }
    __syncthreads();

    // ---- a_i (wave-cooperative, redundant per wave) + bias ----
    float part = x[i * D0 + lane] * mlp_w[lane] + x[i * D0 + 64 + lane] * mlp_w[64 + lane];
    for (int s2 = 32; s2; s2 >>= 1) part += __shfl_down(part, s2);
    const float arb = __shfl(part, 0) + mlp_b[0];

    // ---- score dots split across waves: depth ~np/4 ----
    const int npc = min(np, PMAX);
    for (int p = w; p < npc; p += 4) {
        int j = plj[p], e = ple[p];                  // wave-uniform (LDS broadcast)
        float pp = x[j * D0 + lane] * mlp_w[128 + lane]
                 + x[j * D0 + 64 + lane] * mlp_w[192 + lane];
        if (lane < 16) pp += ea[e * EDIM + lane] * mlp_w[2 * D0 + lane];
        for (int s2 = 32; s2; s2 >>= 1) pp += __shfl_down(pp, s2);
        if (lane == 0) sv[j] = pp + arb;
    }
    __syncthreads();

    // ---- wave w owns columns [w*256, w*256+256): load into registers ----
    float val[4];
    float lm = NEGINF;
    #pragma unroll
    for (int q = 0; q < 4; q++) {
        val[q] = sv[w * 256 + q * 64 + lane];
        lm = fmaxf(lm, val[q]);
    }
    for (int s2 = 32; s2; s2 >>= 1) lm = fmaxf(lm, __shfl_down(lm, s2));
    if (lane == 0) wred[w] = lm;
    __syncthreads();
    const float rowmax = fmaxf(fmaxf(wred[0], wred[1]), fmaxf(wred[2], wred[3]));
    const bool noedge = (rowmax == NEGINF);

    float ls = 0.f;
    #pragma unroll
    for (int q = 0; q < 4; q++) {
        float ev = noedge ? 1.0f : ((val[q] == NEGINF) ? 0.0f : expf(val[q] - rowmax));
        val[q] = ev; ls += ev;
    }
    for (int s2 = 32; s2; s2 >>= 1) ls += __shfl_down(ls, s2);
    if (lane == 0) wred[4 + w] = ls;   // disjoint slots
    __syncthreads();
    const float rsum = wred[4] + wred[5] + wred[6] + wred[7];

    // ---- gumbel: val = z + g (softmax monotone -> same top-k) ----
    const float* ur = u + i * NN + w * 256;
    #pragma unroll
    for (int q = 0; q < 4; q++) {
        float uu = ur[q * 64 + lane];
        float g = -logf(-logf(uu + 1e-20f) + 1e-20f);
        val[q] = val[q] / rsum + g;
    }

    // ---- per-wave top-8 (barrier-free, register-resident) ----
    for (int sel = 0; sel < KTOP; sel++) {
        float bv = -FLT_MAX; int bj = NN;
        #pragma unroll
        for (int q = 0; q < 4; q++) amx(bv, bj, val[q], w * 256 + q * 64 + lane);
        for (int s2 = 32; s2; s2 >>= 1) {
            float ov = __shfl_down(bv, s2); int oj = __shfl_down(bj, s2);
            amx(bv, bj, ov, oj);
        }
        int wj = __shfl(bj, 0);
        if (lane == 0) { candv[w * KTOP + sel] = bv; candj[w * KTOP + sel] = bj; }
        #pragma unroll
        for (int q = 0; q < 4; q++)
            if (w * 256 + q * 64 + lane == wj) val[q] = -FLT_MAX;
    }
    __syncthreads();

    // ---- wave 0 merges 32 candidates (distinct j) into global top-8 ----
    if (w == 0) {
        float mv = (lane < 32) ? candv[lane] : -FLT_MAX;
        int   mj = (lane < 32) ? candj[lane] : NN;
        for (int sel = 0; sel < KTOP; sel++) {
            float bv = mv; int bj = mj;
            for (int s2 = 32; s2; s2 >>= 1) {
                float ov = __shfl_down(bv, s2); int oj = __shfl_down(bj, s2);
                amx(bv, bj, ov, oj);
            }
            int wj = __shfl(bj, 0);
            if (lane == 0) {
                int mn = idmn[wj];
                em[i * KTOP + sel] = (mn == 0x7FFFFFFF) ? 0 : mn;  // no edge -> argmax(all-false)=0
                nd[i * KTOP + sel] = wj;
            }
            if (mj == wj) mv = -FLT_MAX;
        }
    }
}

// ============================================================================
// Kernel 2: GENConv1 fused. 512 blocks, 2 dst rows per block (d = t&127).
// Incoming list built by scanning nd[8192] (L2-broadcast), sorted for determinism.
// ============================================================================
__global__ __launch_bounds__(256) void genconv1_kernel(
    const float* __restrict__ x, const float* __restrict__ ea,
    const float* __restrict__ we_g, const float* __restrict__ be,
    const float* __restrict__ w1, const float* __restrict__ b1,
    const float* __restrict__ w2, const float* __restrict__ b2,
    const int* __restrict__ nd, const int* __restrict__ em,
    float* __restrict__ h)
{
    __shared__ int   slots[2][MAXDEG];
    __shared__ float eatt[2][MAXDEG * EDIM];
    __shared__ float arow[2][D0];
    __shared__ float t1s[2][2 * D0];
    __shared__ int   cnts[2];
    const int t = threadIdx.x, sub = t >> 7, d = t & 127;
    const int r0 = blockIdx.x * 2;
    const int r = r0 + sub;
    if (t < 2) cnts[t] = 0;
    __syncthreads();

    // scan all 8192 selections for matches to this block's 2 rows
    const int4* nd4 = (const int4*)nd;
    #pragma unroll
    for (int q = 0; q < 8; q++) {
        int idx4 = t + q * 256;
        int4 v = nd4[idx4];
        int n0 = idx4 * 4;
        #pragma unroll
        for (int c = 0; c < 4; c++) {
            int dj = (c == 0) ? v.x : (c == 1) ? v.y : (c == 2) ? v.z : v.w;
            unsigned rr = (unsigned)(dj - r0);
            if (rr < 2u) {
                int p = atomicAdd(&cnts[rr], 1);
                if (p < MAXDEG) slots[rr][p] = n0 + c;
            }
        }
    }
    __syncthreads();
    const int cnt = min(cnts[sub], MAXDEG);
    if (d == 0) {  // ascending-n order (deterministic)
        for (int p = 1; p < cnt; p++) {
            int v = slots[sub][p]; int q = p - 1;
            while (q >= 0 && slots[sub][q] > v) { slots[sub][q + 1] = slots[sub][q]; q--; }
            slots[sub][q + 1] = v;
        }
    }
    __syncthreads();
    for (int q = d; q < cnt * EDIM; q += 128)
        eatt[sub][q] = ea[em[slots[sub][q >> 4]] * EDIM + (q & 15)];
    __syncthreads();

    float wed[EDIM];
    #pragma unroll
    for (int k = 0; k < EDIM; k++) wed[k] = we_g[k * D0 + d];
    const float bed = be[d];

    float mxv = -FLT_MAX;
    for (int idx = 0; idx < cnt; idx++) {
        int src = slots[sub][idx] >> 3;
        float ep = bed;
        #pragma unroll
        for (int k = 0; k < EDIM; k++) ep += eatt[sub][idx * EDIM + k] * wed[k];
        float m = fmaxf(x[src * D0 + d] + ep, 0.f) + 1e-7f;
        mxv = fmaxf(mxv, m);
    }
    float den = 0.f, num = 0.f;
    for (int idx = 0; idx < cnt; idx++) {
        int src = slots[sub][idx] >> 3;
        float ep = bed;
        #pragma unroll
        for (int k = 0; k < EDIM; k++) ep += eatt[sub][idx * EDIM + k] * wed[k];
        float m = fmaxf(x[src * D0 + d] + ep, 0.f) + 1e-7f;
        float w = expf(m - mxv);
        den += w; num += w * m;
    }
    float agg = cnt ? num / (den > 0.f ? den : 1.f) : 0.f;
    arow[sub][d] = agg + x[r * D0 + d];
    __syncthreads();

    float acc0 = b1[d], acc1 = b1[d + D0];
    for (int k = 0; k < D0; k++) {
        float av = arow[sub][k];
        acc0 += av * w1[k * 2 * D0 + d];
        acc1 += av * w1[k * 2 * D0 + d + D0];
    }
    t1s[sub][d] = fmaxf(acc0, 0.f);
    t1s[sub][d + D0] = fmaxf(acc1, 0.f);
    __syncthreads();
    if (d < NH1) {
        float acc = b2[d];
        for (int k = 0; k < 2 * D0; k++) acc += t1s[sub][k] * w2[k * NH1 + d];
        h[r * NH1 + d] = fmaxf(acc, 0.f);
    }
}

// ============================================================================
// Kernel 3: GENConv2 + head. 256 blocks, 4 dst rows per block (d = t&63).
// ============================================================================
__global__ __launch_bounds__(256) void genconv2_kernel(
    const float* __restrict__ h, const float* __restrict__ ea,
    const float* __restrict__ we_g, const float* __restrict__ be,
    const float* __restrict__ w1, const float* __restrict__ b1,
    const float* __restrict__ w2, const float* __restrict__ b2,
    const float* __restrict__ fcw, const float* __restrict__ fcb,
    const int* __restrict__ nd, const int* __restrict__ em,
    const int* __restrict__ mask, float* __restrict__ out)
{
    __shared__ int   slots[4][MAXDEG];
    __shared__ float eatt[4][MAXDEG * EDIM];
    __shared__ float arow[4][NH1];
    __shared__ float t2s[4][2 * NH1];
    __shared__ float h2s[4][NH1];
    __shared__ int   cnts[4];
    const int t = threadIdx.x, sub = t >> 6, d = t & 63;
    const int r0 = blockIdx.x * 4;
    const int r = r0 + sub;
    if (t < 4) cnts[t] = 0;
    __syncthreads();

    const int4* nd4 = (const int4*)nd;
    #pragma unroll
    for (int q = 0; q < 8; q++) {
        int idx4 = t + q * 256;
        int4 v = nd4[idx4];
        int n0 = idx4 * 4;
        #pragma unroll
        for (int c = 0; c < 4; c++) {
            int dj = (c == 0) ? v.x : (c == 1) ? v.y : (c == 2) ? v.z : v.w;
            unsigned rr = (unsigned)(dj - r0);
            if (rr < 4u) {
                int p = atomicAdd(&cnts[rr], 1);
                if (p < MAXDEG) slots[rr][p] = n0 + c;
            }
        }
    }
    __syncthreads();
    const int cnt = min(cnts[sub], MAXDEG);
    if (d == 0) {
        for (int p = 1; p < cnt; p++) {
            int v = slots[sub][p]; int q = p - 1;
            while (q >= 0 && slots[sub][q] > v) { slots[sub][q + 1] = slots[sub][q]; q--; }
            slots[sub][q + 1] = v;
        }
    }
    __syncthreads();
    for (int q = d; q < cnt * EDIM; q += 64)
        eatt[sub][q] = ea[em[slots[sub][q >> 4]] * EDIM + (q & 15)];
    __syncthreads();

    float wed[EDIM];
    #pragma unroll
    for (int k = 0; k < EDIM; k++) wed[k] = we_g[k * NH1 + d];
    const float bed = be[d];

    float mxv = -FLT_MAX;
    for (int idx = 0; idx < cnt; idx++) {
        int src = slots[sub][idx] >> 3;
        float ep = bed;
        #pragma unroll
        for (int k = 0; k < EDIM; k++) ep += eatt[sub][idx * EDIM + k] * wed[k];
        float m = fmaxf(h[src * NH1 + d] + ep, 0.f) + 1e-7f;
        mxv = fmaxf(mxv, m);
    }
    float den = 0.f, num = 0.f;
    for (int idx = 0; idx < cnt; idx++) {
        int src = slots[sub][idx] >> 3;
        float ep = bed;
        #pragma unroll
        for (int k = 0; k < EDIM; k++) ep += eatt[sub][idx * EDIM + k] * wed[k];
        float m = fmaxf(h[src * NH1 + d] + ep, 0.f) + 1e-7f;
        float w = expf(m - mxv);
        den += w; num += w * m;
    }
    float agg = cnt ? num / (den > 0.f ? den : 1.f) : 0.f;
    arow[sub][d] = agg + h[r * NH1 + d];
    __syncthreads();

    {
        float acc_a = b1[d], acc_b = b1[d + NH1];
        for (int k = 0; k < NH1; k++) {
            float av = arow[sub][k];
            acc_a += av * w1[k * 2 * NH1 + d];
            acc_b += av * w1[k * 2 * NH1 + d + NH1];
        }
        t2s[sub][d] = fmaxf(acc_a, 0.f);
        t2s[sub][d + NH1] = fmaxf(acc_b, 0.f);
    }
    __syncthreads();
    {
        float acc = b2[d];
        for (int k = 0; k < 2 * NH1; k++) acc += t2s[sub][k] * w2[k * NH1 + d];
        h2s[sub][d] = fmaxf(acc, 0.f);
    }
    __syncthreads();
    if (d < NOUT) {
        float acc = fcb[d];
        for (int k = 0; k < NH1; k++) acc += h2s[sub][k] * fcw[k * NOUT + d];
        out[r * NOUT + d] = (mask[r] != 0) ? acc : 0.f;
    }
}

extern "C" void kernel_launch(void* const* d_in, const int* in_sizes, int n_in,
                              void* d_out, int out_size, void* d_ws, size_t ws_size,
                              hipStream_t stream) {
    const float* x      = (const float*)d_in[0];
    const float* ea     = (const float*)d_in[1];
    const float* u      = (const float*)d_in[2];
    const float* mlp_w  = (const float*)d_in[3];
    const float* mlp_b  = (const float*)d_in[4];
    const float* c1_we  = (const float*)d_in[5];
    const float* c1_be  = (const float*)d_in[6];
    const float* c1_w1  = (const float*)d_in[7];
    const float* c1_b1  = (const float*)d_in[8];
    const float* c1_w2  = (const float*)d_in[9];
    const float* c1_b2  = (const float*)d_in[10];
    const float* c2_we  = (const float*)d_in[11];
    const float* c2_be  = (const float*)d_in[12];
    const float* c2_w1  = (const float*)d_in[13];
    const float* c2_b1  = (const float*)d_in[14];
    const float* c2_w2  = (const float*)d_in[15];
    const float* c2_b2  = (const float*)d_in[16];
    const float* fc_w   = (const float*)d_in[17];
    const float* fc_b   = (const float*)d_in[18];
    const int*   ei     = (const int*)d_in[20];
    const int*   mask   = (const int*)d_in[21];

    char* ws = (char*)d_ws;
    int*   em = (int*)(ws + OFF_EM);
    int*   nd = (int*)(ws + OFF_ND);
    float* h  = (float*)(ws + OFF_H);
    float* out = (float*)d_out;

    // 3 dispatches, no memset, no global atomics, no device barriers.
    topk_kernel<<<NN, 256, 0, stream>>>(x, ea, u, mlp_w, mlp_b, ei, nd, em);
    genconv1_kernel<<<NN / 2, 256, 0, stream>>>(x, ea, c1_we, c1_be, c1_w1, c1_b1, c1_w2, c1_b2,
                                                nd, em, h);
    genconv2_kernel<<<NN / 4, 256, 0, stream>>>(h, ea, c2_we, c2_be, c2_w1, c2_b1, c2_w2, c2_b2,
                                                fc_w, fc_b, nd, em, mask, out);
}

// Round 4
// 159.029 us; speedup vs baseline: 5.0576x; 1.0186x over previous
//
#include <hip/hip_runtime.h>
#include <cfloat>

#define NN   1024
#define NE   16384
#define D0   128
#define EDIM 16
#define NH1  64
#define NOUT 40
#define KTOP 8
#define NEGINF (-1000000000.0f)
#define MAXDEG 64   // in-deg of selected graph ~ Poisson(8); P(>64) negligible
#define PMAX   64   // distinct-dst count per src row ~ Poisson(16); P(>64) negligible

// ---- workspace layout (bytes); everything written-before-read, no memset ----
#define OFF_EM  0u        // 8192 int  (edge id per selection)
#define OFF_ND  32768u    // 8192 int  (new_dst per selection)
#define OFF_H   65536u    // 1024*64 f (GENConv1 output)

__device__ __forceinline__ void amx(float& v, int& j, float ov, int oj) {
    if (ov > v || (ov == v && oj < j)) { v = ov; j = oj; }
}

// ============================================================================
// Kernel 1: per-row score + gumbel + top-8.  1024 blocks x 512 threads
// (one block per row: 8 waves/block, 4 blocks/CU -> 32 waves/CU = 100% cap).
//  - u prefetched to regs at entry (only HBM-cold read; hidden under scan)
//  - edge scan: src int4 (8/thread); dst scalar only on match
//  - score dots: 16-lane groups, 32 concurrent pairs -> serial depth 1 for
//    np~16 (was 4), 4-step width-16 reduce (was 6-step width-64)
//  - per-wave register top-8 (8x8=64 candidates) -> one 64-lane merge
// ============================================================================
__global__ __launch_bounds__(512) void topk_kernel(
    const float* __restrict__ x, const float* __restrict__ ea,
    const float* __restrict__ u, const float* __restrict__ mlp_w,
    const float* __restrict__ mlp_b, const int* __restrict__ ei,
    int* __restrict__ nd, int* __restrict__ em)
{
    __shared__ int   idmx[NN];      // max edge id per dst, -1 = none
    __shared__ int   idmn[NN];      // min edge id per dst
    __shared__ float sv[NN];        // scores (NEGINF = unmatched)
    __shared__ int   plj[PMAX];     // matched column list
    __shared__ int   ple[PMAX];     // matched edge (max id)
    __shared__ int   np;
    __shared__ float wred[16];      // [0..7] max, [8..15] sum
    __shared__ float candv[64];
    __shared__ int   candj[64];
    const int i = blockIdx.x, t = threadIdx.x;
    const int lane = t & 63, w = t >> 6;          // wave 0..7
    const int subl = t & 15;                      // lane within 16-group
    const int gg = t >> 4;                        // group 0..31

    // ---- prefetch u (HBM-cold) into regs: columns w*128 + {0,64} + lane ----
    float uval[2];
    uval[0] = u[i * NN + w * 128 + lane];
    uval[1] = u[i * NN + w * 128 + 64 + lane];

    #pragma unroll
    for (int q = 0; q < 2; q++) {
        int j = t + q * 512;
        idmx[j] = -1; idmn[j] = 0x7FFFFFFF; sv[j] = NEGINF;
    }
    if (t == 0) np = 0;
    __syncthreads();

    // ---- edge scan: src int4 (8 per thread); dst scalar only on match ----
    const int4* s4 = (const int4*)ei;
    #pragma unroll
    for (int q = 0; q < 8; q++) {
        int idx4 = t + q * 512;
        int4 sv4 = s4[idx4];
        int e0 = idx4 * 4;
        if (sv4.x == i) { int dj = ei[NE + e0 + 0]; atomicMax(&idmx[dj], e0 + 0); atomicMin(&idmn[dj], e0 + 0); }
        if (sv4.y == i) { int dj = ei[NE + e0 + 1]; atomicMax(&idmx[dj], e0 + 1); atomicMin(&idmn[dj], e0 + 1); }
        if (sv4.z == i) { int dj = ei[NE + e0 + 2]; atomicMax(&idmx[dj], e0 + 2); atomicMin(&idmn[dj], e0 + 2); }
        if (sv4.w == i) { int dj = ei[NE + e0 + 3]; atomicMax(&idmx[dj], e0 + 3); atomicMin(&idmn[dj], e0 + 3); }
    }
    __syncthreads();

    // ---- compact matched columns ----
    #pragma unroll
    for (int q = 0; q < 2; q++) {
        int j = t + q * 512;
        int e = idmx[j];
        if (e >= 0) {
            int p = atomicAdd(&np, 1);
            if (p < PMAX) { plj[p] = j; ple[p] = e; }
        }
    }
    __syncthreads();

    // ---- a_i (wave-cooperative, redundant per wave) + bias ----
    float part = x[i * D0 + lane] * mlp_w[lane] + x[i * D0 + 64 + lane] * mlp_w[64 + lane];
    for (int s2 = 32; s2; s2 >>= 1) part += __shfl_down(part, s2);
    const float arb = __shfl(part, 0) + mlp_b[0];

    // ---- score dots: one 16-lane group per pair, 32 pairs concurrent ----
    const int npc = min(np, PMAX);
    for (int p = gg; p < npc; p += 32) {
        int j = plj[p], e = ple[p];               // group-uniform (LDS broadcast)
        float pp = ea[e * EDIM + subl] * mlp_w[2 * D0 + subl];
        #pragma unroll
        for (int k = 0; k < 8; k++)
            pp += x[j * D0 + subl + k * 16] * mlp_w[D0 + subl + k * 16];
        #pragma unroll
        for (int s2 = 8; s2; s2 >>= 1) pp += __shfl_down(pp, s2, 16);
        if (subl == 0) sv[j] = pp + arb;
    }
    __syncthreads();

    // ---- wave w owns columns [w*128, w*128+128) ----
    float val[2];
    val[0] = sv[w * 128 + lane];
    val[1] = sv[w * 128 + 64 + lane];
    float lm = fmaxf(val[0], val[1]);
    for (int s2 = 32; s2; s2 >>= 1) lm = fmaxf(lm, __shfl_down(lm, s2));
    if (lane == 0) wred[w] = lm;
    __syncthreads();
    float rowmax = wred[0];
    #pragma unroll
    for (int q = 1; q < 8; q++) rowmax = fmaxf(rowmax, wred[q]);
    const bool noedge = (rowmax == NEGINF);

    float ls = 0.f;
    #pragma unroll
    for (int q = 0; q < 2; q++) {
        float ev = noedge ? 1.0f : ((val[q] == NEGINF) ? 0.0f : expf(val[q] - rowmax));
        val[q] = ev; ls += ev;
    }
    for (int s2 = 32; s2; s2 >>= 1) ls += __shfl_down(ls, s2);
    if (lane == 0) wred[8 + w] = ls;   // disjoint slots
    __syncthreads();
    float rsum = wred[8];
    #pragma unroll
    for (int q = 1; q < 8; q++) rsum += wred[8 + q];

    // ---- gumbel: val = z + g (softmax monotone -> same top-k) ----
    #pragma unroll
    for (int q = 0; q < 2; q++) {
        float g = -logf(-logf(uval[q] + 1e-20f) + 1e-20f);
        val[q] = val[q] / rsum + g;
    }

    // ---- per-wave top-8 over 128 columns (barrier-free, register-resident) ----
    for (int sel = 0; sel < KTOP; sel++) {
        float bv = -FLT_MAX; int bj = NN;
        amx(bv, bj, val[0], w * 128 + lane);
        amx(bv, bj, val[1], w * 128 + 64 + lane);
        for (int s2 = 32; s2; s2 >>= 1) {
            float ov = __shfl_down(bv, s2); int oj = __shfl_down(bj, s2);
            amx(bv, bj, ov, oj);
        }
        int wj = __shfl(bj, 0);
        if (lane == 0) { candv[w * KTOP + sel] = bv; candj[w * KTOP + sel] = bj; }
        if (w * 128 + lane == wj) val[0] = -FLT_MAX;
        if (w * 128 + 64 + lane == wj) val[1] = -FLT_MAX;
    }
    __syncthreads();

    // ---- wave 0: merge 64 candidates (all distinct j) into global top-8 ----
    if (w == 0) {
        float mv = candv[lane];
        int   mj = candj[lane];
        for (int sel = 0; sel < KTOP; sel++) {
            float bv = mv; int bj = mj;
            for (int s2 = 32; s2; s2 >>= 1) {
                float ov = __shfl_down(bv, s2); int oj = __shfl_down(bj, s2);
                amx(bv, bj, ov, oj);
            }
            int wj = __shfl(bj, 0);
            if (lane == 0) {
                int mn = idmn[wj];
                em[i * KTOP + sel] = (mn == 0x7FFFFFFF) ? 0 : mn;  // no edge -> argmax(all-false)=0
                nd[i * KTOP + sel] = wj;
            }
            if (mj == wj) mv = -FLT_MAX;
        }
    }
}

// ============================================================================
// Kernel 2: GENConv1 fused. 512 blocks, 2 dst rows per block (d = t&127).
// Incoming list built by scanning nd[8192] (L2-broadcast), sorted for determinism.
// ============================================================================
__global__ __launch_bounds__(256) void genconv1_kernel(
    const float* __restrict__ x, const float* __restrict__ ea,
    const float* __restrict__ we_g, const float* __restrict__ be,
    const float* __restrict__ w1, const float* __restrict__ b1,
    const float* __restrict__ w2, const float* __restrict__ b2,
    const int* __restrict__ nd, const int* __restrict__ em,
    float* __restrict__ h)
{
    __shared__ int   slots[2][MAXDEG];
    __shared__ float eatt[2][MAXDEG * EDIM];
    __shared__ float arow[2][D0];
    __shared__ float t1s[2][2 * D0];
    __shared__ int   cnts[2];
    const int t = threadIdx.x, sub = t >> 7, d = t & 127;
    const int r0 = blockIdx.x * 2;
    const int r = r0 + sub;
    if (t < 2) cnts[t] = 0;
    __syncthreads();

    // scan all 8192 selections for matches to this block's 2 rows
    const int4* nd4 = (const int4*)nd;
    #pragma unroll
    for (int q = 0; q < 8; q++) {
        int idx4 = t + q * 256;
        int4 v = nd4[idx4];
        int n0 = idx4 * 4;
        #pragma unroll
        for (int c = 0; c < 4; c++) {
            int dj = (c == 0) ? v.x : (c == 1) ? v.y : (c == 2) ? v.z : v.w;
            unsigned rr = (unsigned)(dj - r0);
            if (rr < 2u) {
                int p = atomicAdd(&cnts[rr], 1);
                if (p < MAXDEG) slots[rr][p] = n0 + c;
            }
        }
    }
    __syncthreads();
    const int cnt = min(cnts[sub], MAXDEG);
    if (d == 0) {  // ascending-n order (deterministic)
        for (int p = 1; p < cnt; p++) {
            int v = slots[sub][p]; int q = p - 1;
            while (q >= 0 && slots[sub][q] > v) { slots[sub][q + 1] = slots[sub][q]; q--; }
            slots[sub][q + 1] = v;
        }
    }
    __syncthreads();
    for (int q = d; q < cnt * EDIM; q += 128)
        eatt[sub][q] = ea[em[slots[sub][q >> 4]] * EDIM + (q & 15)];
    __syncthreads();

    float wed[EDIM];
    #pragma unroll
    for (int k = 0; k < EDIM; k++) wed[k] = we_g[k * D0 + d];
    const float bed = be[d];

    float mxv = -FLT_MAX;
    for (int idx = 0; idx < cnt; idx++) {
        int src = slots[sub][idx] >> 3;
        float ep = bed;
        #pragma unroll
        for (int k = 0; k < EDIM; k++) ep += eatt[sub][idx * EDIM + k] * wed[k];
        float m = fmaxf(x[src * D0 + d] + ep, 0.f) + 1e-7f;
        mxv = fmaxf(mxv, m);
    }
    float den = 0.f, num = 0.f;
    for (int idx = 0; idx < cnt; idx++) {
        int src = slots[sub][idx] >> 3;
        float ep = bed;
        #pragma unroll
        for (int k = 0; k < EDIM; k++) ep += eatt[sub][idx * EDIM + k] * wed[k];
        float m = fmaxf(x[src * D0 + d] + ep, 0.f) + 1e-7f;
        float w = expf(m - mxv);
        den += w; num += w * m;
    }
    float agg = cnt ? num / (den > 0.f ? den : 1.f) : 0.f;
    arow[sub][d] = agg + x[r * D0 + d];
    __syncthreads();

    float acc0 = b1[d], acc1 = b1[d + D0];
    for (int k = 0; k < D0; k++) {
        float av = arow[sub][k];
        acc0 += av * w1[k * 2 * D0 + d];
        acc1 += av * w1[k * 2 * D0 + d + D0];
    }
    t1s[sub][d] = fmaxf(acc0, 0.f);
    t1s[sub][d + D0] = fmaxf(acc1, 0.f);
    __syncthreads();
    if (d < NH1) {
        float acc = b2[d];
        for (int k = 0; k < 2 * D0; k++) acc += t1s[sub][k] * w2[k * NH1 + d];
        h[r * NH1 + d] = fmaxf(acc, 0.f);
    }
}

// ============================================================================
// Kernel 3: GENConv2 + head. 256 blocks, 4 dst rows per block (d = t&63).
// ============================================================================
__global__ __launch_bounds__(256) void genconv2_kernel(
    const float* __restrict__ h, const float* __restrict__ ea,
    const float* __restrict__ we_g, const float* __restrict__ be,
    const float* __restrict__ w1, const float* __restrict__ b1,
    const float* __restrict__ w2, const float* __restrict__ b2,
    const float* __restrict__ fcw, const float* __restrict__ fcb,
    const int* __restrict__ nd, const int* __restrict__ em,
    const int* __restrict__ mask, float* __restrict__ out)
{
    __shared__ int   slots[4][MAXDEG];
    __shared__ float eatt[4][MAXDEG * EDIM];
    __shared__ float arow[4][NH1];
    __shared__ float t2s[4][2 * NH1];
    __shared__ float h2s[4][NH1];
    __shared__ int   cnts[4];
    const int t = threadIdx.x, sub = t >> 6, d = t & 63;
    const int r0 = blockIdx.x * 4;
    const int r = r0 + sub;
    if (t < 4) cnts[t] = 0;
    __syncthreads();

    const int4* nd4 = (const int4*)nd;
    #pragma unroll
    for (int q = 0; q < 8; q++) {
        int idx4 = t + q * 256;
        int4 v = nd4[idx4];
        int n0 = idx4 * 4;
        #pragma unroll
        for (int c = 0; c < 4; c++) {
            int dj = (c == 0) ? v.x : (c == 1) ? v.y : (c == 2) ? v.z : v.w;
            unsigned rr = (unsigned)(dj - r0);
            if (rr < 4u) {
                int p = atomicAdd(&cnts[rr], 1);
                if (p < MAXDEG) slots[rr][p] = n0 + c;
            }
        }
    }
    __syncthreads();
    const int cnt = min(cnts[sub], MAXDEG);
    if (d == 0) {
        for (int p = 1; p < cnt; p++) {
            int v = slots[sub][p]; int q = p - 1;
            while (q >= 0 && slots[sub][q] > v) { slots[sub][q + 1] = slots[sub][q]; q--; }
            slots[sub][q + 1] = v;
        }
    }
    __syncthreads();
    for (int q = d; q < cnt * EDIM; q += 64)
        eatt[sub][q] = ea[em[slots[sub][q >> 4]] * EDIM + (q & 15)];
    __syncthreads();

    float wed[EDIM];
    #pragma unroll
    for (int k = 0; k < EDIM; k++) wed[k] = we_g[k * NH1 + d];
    const float bed = be[d];

    float mxv = -FLT_MAX;
    for (int idx = 0; idx < cnt; idx++) {
        int src = slots[sub][idx] >> 3;
        float ep = bed;
        #pragma unroll
        for (int k = 0; k < EDIM; k++) ep += eatt[sub][idx * EDIM + k] * wed[k];
        float m = fmaxf(h[src * NH1 + d] + ep, 0.f) + 1e-7f;
        mxv = fmaxf(mxv, m);
    }
    float den = 0.f, num = 0.f;
    for (int idx = 0; idx < cnt; idx++) {
        int src = slots[sub][idx] >> 3;
        float ep = bed;
        #pragma unroll
        for (int k = 0; k < EDIM; k++) ep += eatt[sub][idx * EDIM + k] * wed[k];
        float m = fmaxf(h[src * NH1 + d] + ep, 0.f) + 1e-7f;
        float w = expf(m - mxv);
        den += w; num += w * m;
    }
    float agg = cnt ? num / (den > 0.f ? den : 1.f) : 0.f;
    arow[sub][d] = agg + h[r * NH1 + d];
    __syncthreads();

    {
        float acc_a = b1[d], acc_b = b1[d + NH1];
        for (int k = 0; k < NH1; k++) {
            float av = arow[sub][k];
            acc_a += av * w1[k * 2 * NH1 + d];
            acc_b += av * w1[k * 2 * NH1 + d + NH1];
        }
        t2s[sub][d] = fmaxf(acc_a, 0.f);
        t2s[sub][d + NH1] = fmaxf(acc_b, 0.f);
    }
    __syncthreads();
    {
        float acc = b2[d];
        for (int k = 0; k < 2 * NH1; k++) acc += t2s[sub][k] * w2[k * NH1 + d];
        h2s[sub][d] = fmaxf(acc, 0.f);
    }
    __syncthreads();
    if (d < NOUT) {
        float acc = fcb[d];
        for (int k = 0; k < NH1; k++) acc += h2s[sub][k] * fcw[k * NOUT + d];
        out[r * NOUT + d] = (mask[r] != 0) ? acc : 0.f;
    }
}

extern "C" void kernel_launch(void* const* d_in, const int* in_sizes, int n_in,
                              void* d_out, int out_size, void* d_ws, size_t ws_size,
                              hipStream_t stream) {
    const float* x      = (const float*)d_in[0];
    const float* ea     = (const float*)d_in[1];
    const float* u      = (const float*)d_in[2];
    const float* mlp_w  = (const float*)d_in[3];
    const float* mlp_b  = (const float*)d_in[4];
    const float* c1_we  = (const float*)d_in[5];
    const float* c1_be  = (const float*)d_in[6];
    const float* c1_w1  = (const float*)d_in[7];
    const float* c1_b1  = (const float*)d_in[8];
    const float* c1_w2  = (const float*)d_in[9];
    const float* c1_b2  = (const float*)d_in[10];
    const float* c2_we  = (const float*)d_in[11];
    const float* c2_be  = (const float*)d_in[12];
    const float* c2_w1  = (const float*)d_in[13];
    const float* c2_b1  = (const float*)d_in[14];
    const float* c2_w2  = (const float*)d_in[15];
    const float* c2_b2  = (const float*)d_in[16];
    const float* fc_w   = (const float*)d_in[17];
    const float* fc_b   = (const float*)d_in[18];
    const int*   ei     = (const int*)d_in[20];
    const int*   mask   = (const int*)d_in[21];

    char* ws = (char*)d_ws;
    int*   em = (int*)(ws + OFF_EM);
    int*   nd = (int*)(ws + OFF_ND);
    float* h  = (float*)(ws + OFF_H);
    float* out = (float*)d_out;

    // 3 dispatches, no memset, no global atomics, no device barriers.
    topk_kernel<<<NN, 512, 0, stream>>>(x, ea, u, mlp_w, mlp_b, ei, nd, em);
    genconv1_kernel<<<NN / 2, 256, 0, stream>>>(x, ea, c1_we, c1_be, c1_w1, c1_b1, c1_w2, c1_b2,
                                                nd, em, h);
    genconv2_kernel<<<NN / 4, 256, 0, stream>>>(h, ea, c2_we, c2_be, c2_w1, c2_b1, c2_w2, c2_b2,
                                                fc_w, fc_b, nd, em, mask, out);
}

// Round 5
// 156.396 us; speedup vs baseline: 5.1427x; 1.0168x over previous
//
#include <hip/hip_runtime.h>
#include <cfloat>

#define NN   1024
#define NE   16384
#define D0   128
#define EDIM 16
#define NH1  64
#define NOUT 40
#define KTOP 8
#define NEGINF (-1000000000.0f)
#define MAXDEG 64   // in-deg of selected graph ~ Poisson(8); P(>64) negligible
#define PMAX   64   // distinct-dst count per src row ~ Poisson(16); P(>64) negligible

// ---- workspace layout (bytes); everything written-before-read, no memset ----
#define OFF_EM  0u        // 8192 int  (edge id per selection)
#define OFF_ND  32768u    // 8192 int  (new_dst per selection)
#define OFF_H   65536u    // 1024*64 f (GENConv1 output)

__device__ __forceinline__ void amx(float& v, int& j, float ov, int oj) {
    if (ov > v || (ov == v && oj < j)) { v = ov; j = oj; }
}

// ============================================================================
// Kernel 1: per-row score + gumbel + top-8.  1024 blocks x 512 threads.
// NOTE: this kernel runs concurrently with the harness poison-fill's L2->HBM
// writeback drain (~40 us), so it is drain-bound, not compute-bound. Its tail
// (waves 1-7, idle during the wave-0 merge) prefetches x/ea/w1 into L2/L3 so
// genconv1 starts warm (the drain is finished by then).
// ============================================================================
__global__ __launch_bounds__(512) void topk_kernel(
    const float* __restrict__ x, const float* __restrict__ ea,
    const float* __restrict__ u, const float* __restrict__ mlp_w,
    const float* __restrict__ mlp_b, const int* __restrict__ ei,
    const float* __restrict__ c1w1,   // prefetch-only
    int* __restrict__ nd, int* __restrict__ em)
{
    __shared__ int   idmx[NN];      // max edge id per dst, -1 = none
    __shared__ int   idmn[NN];      // min edge id per dst
    __shared__ float sv[NN];        // scores (NEGINF = unmatched)
    __shared__ int   plj[PMAX];     // matched column list
    __shared__ int   ple[PMAX];     // matched edge (max id)
    __shared__ int   np;
    __shared__ float wred[16];      // [0..7] max, [8..15] sum
    __shared__ float candv[64];
    __shared__ int   candj[64];
    const int i = blockIdx.x, t = threadIdx.x;
    const int lane = t & 63, w = t >> 6;          // wave 0..7
    const int subl = t & 15;                      // lane within 16-group
    const int gg = t >> 4;                        // group 0..31

    // ---- prefetch u (HBM-cold) into regs: columns w*128 + {0,64} + lane ----
    float uval[2];
    uval[0] = u[i * NN + w * 128 + lane];
    uval[1] = u[i * NN + w * 128 + 64 + lane];

    #pragma unroll
    for (int q = 0; q < 2; q++) {
        int j = t + q * 512;
        idmx[j] = -1; idmn[j] = 0x7FFFFFFF; sv[j] = NEGINF;
    }
    if (t == 0) np = 0;
    __syncthreads();

    // ---- edge scan: src int4 (8 per thread); dst scalar only on match ----
    const int4* s4 = (const int4*)ei;
    #pragma unroll
    for (int q = 0; q < 8; q++) {
        int idx4 = t + q * 512;
        int4 sv4 = s4[idx4];
        int e0 = idx4 * 4;
        if (sv4.x == i) { int dj = ei[NE + e0 + 0]; atomicMax(&idmx[dj], e0 + 0); atomicMin(&idmn[dj], e0 + 0); }
        if (sv4.y == i) { int dj = ei[NE + e0 + 1]; atomicMax(&idmx[dj], e0 + 1); atomicMin(&idmn[dj], e0 + 1); }
        if (sv4.z == i) { int dj = ei[NE + e0 + 2]; atomicMax(&idmx[dj], e0 + 2); atomicMin(&idmn[dj], e0 + 2); }
        if (sv4.w == i) { int dj = ei[NE + e0 + 3]; atomicMax(&idmx[dj], e0 + 3); atomicMin(&idmn[dj], e0 + 3); }
    }
    __syncthreads();

    // ---- compact matched columns ----
    #pragma unroll
    for (int q = 0; q < 2; q++) {
        int j = t + q * 512;
        int e = idmx[j];
        if (e >= 0) {
            int p = atomicAdd(&np, 1);
            if (p < PMAX) { plj[p] = j; ple[p] = e; }
        }
    }
    __syncthreads();

    // ---- a_i (wave-cooperative, redundant per wave) + bias ----
    float part = x[i * D0 + lane] * mlp_w[lane] + x[i * D0 + 64 + lane] * mlp_w[64 + lane];
    for (int s2 = 32; s2; s2 >>= 1) part += __shfl_down(part, s2);
    const float arb = __shfl(part, 0) + mlp_b[0];

    // ---- score dots: one 16-lane group per pair, 32 pairs concurrent ----
    const int npc = min(np, PMAX);
    for (int p = gg; p < npc; p += 32) {
        int j = plj[p], e = ple[p];               // group-uniform (LDS broadcast)
        float pp = ea[e * EDIM + subl] * mlp_w[2 * D0 + subl];
        #pragma unroll
        for (int k = 0; k < 8; k++)
            pp += x[j * D0 + subl + k * 16] * mlp_w[D0 + subl + k * 16];
        #pragma unroll
        for (int s2 = 8; s2; s2 >>= 1) pp += __shfl_down(pp, s2, 16);
        if (subl == 0) sv[j] = pp + arb;
    }
    __syncthreads();

    // ---- wave w owns columns [w*128, w*128+128) ----
    float val[2];
    val[0] = sv[w * 128 + lane];
    val[1] = sv[w * 128 + 64 + lane];
    float lm = fmaxf(val[0], val[1]);
    for (int s2 = 32; s2; s2 >>= 1) lm = fmaxf(lm, __shfl_down(lm, s2));
    if (lane == 0) wred[w] = lm;
    __syncthreads();
    float rowmax = wred[0];
    #pragma unroll
    for (int q = 1; q < 8; q++) rowmax = fmaxf(rowmax, wred[q]);
    const bool noedge = (rowmax == NEGINF);

    float ls = 0.f;
    #pragma unroll
    for (int q = 0; q < 2; q++) {
        float ev = noedge ? 1.0f : ((val[q] == NEGINF) ? 0.0f : expf(val[q] - rowmax));
        val[q] = ev; ls += ev;
    }
    for (int s2 = 32; s2; s2 >>= 1) ls += __shfl_down(ls, s2);
    if (lane == 0) wred[8 + w] = ls;   // disjoint slots
    __syncthreads();
    float rsum = wred[8];
    #pragma unroll
    for (int q = 1; q < 8; q++) rsum += wred[8 + q];

    // ---- gumbel: val = z + g (softmax monotone -> same top-k) ----
    #pragma unroll
    for (int q = 0; q < 2; q++) {
        float g = -logf(-logf(uval[q] + 1e-20f) + 1e-20f);
        val[q] = val[q] / rsum + g;
    }

    // ---- per-wave top-8 over 128 columns (barrier-free, register-resident) ----
    for (int sel = 0; sel < KTOP; sel++) {
        float bv = -FLT_MAX; int bj = NN;
        amx(bv, bj, val[0], w * 128 + lane);
        amx(bv, bj, val[1], w * 128 + 64 + lane);
        for (int s2 = 32; s2; s2 >>= 1) {
            float ov = __shfl_down(bv, s2); int oj = __shfl_down(bj, s2);
            amx(bv, bj, ov, oj);
        }
        int wj = __shfl(bj, 0);
        if (lane == 0) { candv[w * KTOP + sel] = bv; candj[w * KTOP + sel] = bj; }
        if (w * 128 + lane == wj) val[0] = -FLT_MAX;
        if (w * 128 + 64 + lane == wj) val[1] = -FLT_MAX;
    }
    __syncthreads();

    if (w == 0) {
        // ---- wave 0: merge 64 candidates (all distinct j) into global top-8 ----
        float mv = candv[lane];
        int   mj = candj[lane];
        for (int sel = 0; sel < KTOP; sel++) {
            float bv = mv; int bj = mj;
            for (int s2 = 32; s2; s2 >>= 1) {
                float ov = __shfl_down(bv, s2); int oj = __shfl_down(bj, s2);
                amx(bv, bj, ov, oj);
            }
            int wj = __shfl(bj, 0);
            if (lane == 0) {
                int mn = idmn[wj];
                em[i * KTOP + sel] = (mn == 0x7FFFFFFF) ? 0 : mn;  // no edge -> argmax(all-false)=0
                nd[i * KTOP + sel] = wj;
            }
            if (mj == wj) mv = -FLT_MAX;
        }
    } else {
        // ---- waves 1-7 (idle during merge): warm L2/L3 for genconv1.
        // Collectively across 1024 blocks: all of x (512KB), ea (1MB), w1 (128KB).
        // Post-drain, so these run at full BW and are hidden under the merge.
        float pf = 0.f;
        if (t < 192)       pf = x[i * D0 + (t - 64)];          // t in [64,192): x row i
        else if (t < 448)  pf = ea[i * 256 + (t - 192)];       // ea slice [i*256, i*256+256)
        else if (t < 480)  pf = c1w1[i * 32 + (t - 448)];      // w1 slice [i*32, i*32+32)
        asm volatile("" :: "v"(pf));   // keep-alive (rule: ablation-via-skip DCE)
    }
}

// ============================================================================
// Kernel 2: GENConv1 fused. 1024 blocks (ONE dst row each) x 256 threads.
// 4 blocks/CU x 4 waves = 16 waves/CU (2x the old 512-block layout).
// Per-output accumulation order is BIT-IDENTICAL to the verified 2-row version.
// ============================================================================
__global__ __launch_bounds__(256) void genconv1_kernel(
    const float* __restrict__ x, const float* __restrict__ ea,
    const float* __restrict__ we_g, const float* __restrict__ be,
    const float* __restrict__ w1, const float* __restrict__ b1,
    const float* __restrict__ w2, const float* __restrict__ b2,
    const int* __restrict__ nd, const int* __restrict__ em,
    float* __restrict__ h)
{
    __shared__ int   slots[MAXDEG];
    __shared__ float eatt[MAXDEG * EDIM];
    __shared__ float arow[D0];
    __shared__ float t1s[2 * D0];
    __shared__ int   cnt_s;
    const int t = threadIdx.x;
    const int r = blockIdx.x;
    if (t == 0) cnt_s = 0;
    __syncthreads();

    // scan all 8192 selections for matches to this block's row
    const int4* nd4 = (const int4*)nd;
    #pragma unroll
    for (int q = 0; q < 8; q++) {
        int idx4 = t + q * 256;
        int4 v = nd4[idx4];
        int n0 = idx4 * 4;
        if (v.x == r) { int p = atomicAdd(&cnt_s, 1); if (p < MAXDEG) slots[p] = n0 + 0; }
        if (v.y == r) { int p = atomicAdd(&cnt_s, 1); if (p < MAXDEG) slots[p] = n0 + 1; }
        if (v.z == r) { int p = atomicAdd(&cnt_s, 1); if (p < MAXDEG) slots[p] = n0 + 2; }
        if (v.w == r) { int p = atomicAdd(&cnt_s, 1); if (p < MAXDEG) slots[p] = n0 + 3; }
    }
    __syncthreads();
    const int cnt = min(cnt_s, MAXDEG);
    if (t == 0) {  // ascending-n order (deterministic)
        for (int p = 1; p < cnt; p++) {
            int v = slots[p]; int q = p - 1;
            while (q >= 0 && slots[q] > v) { slots[q + 1] = slots[q]; q--; }
            slots[q + 1] = v;
        }
    }
    __syncthreads();
    for (int q = t; q < cnt * EDIM; q += 256)
        eatt[q] = ea[em[slots[q >> 4]] * EDIM + (q & 15)];
    __syncthreads();

    if (t < D0) {
        const int d = t;
        float wed[EDIM];
        #pragma unroll
        for (int k = 0; k < EDIM; k++) wed[k] = we_g[k * D0 + d];
        const float bed = be[d];

        float mxv = -FLT_MAX;
        for (int idx = 0; idx < cnt; idx++) {
            int src = slots[idx] >> 3;
            float ep = bed;
            #pragma unroll
            for (int k = 0; k < EDIM; k++) ep += eatt[idx * EDIM + k] * wed[k];
            float m = fmaxf(x[src * D0 + d] + ep, 0.f) + 1e-7f;
            mxv = fmaxf(mxv, m);
        }
        float den = 0.f, num = 0.f;
        for (int idx = 0; idx < cnt; idx++) {
            int src = slots[idx] >> 3;
            float ep = bed;
            #pragma unroll
            for (int k = 0; k < EDIM; k++) ep += eatt[idx * EDIM + k] * wed[k];
            float m = fmaxf(x[src * D0 + d] + ep, 0.f) + 1e-7f;
            float w = expf(m - mxv);
            den += w; num += w * m;
        }
        float agg = cnt ? num / (den > 0.f ? den : 1.f) : 0.f;
        arow[d] = agg + x[r * D0 + d];
    }
    __syncthreads();

    {   // t1: all 256 outputs, one thread each (exact per-output k-order)
        float acc = b1[t];
        for (int k = 0; k < D0; k++) acc += arow[k] * w1[k * 2 * D0 + t];
        t1s[t] = fmaxf(acc, 0.f);
    }
    __syncthreads();
    if (t < NH1) {
        float acc = b2[t];
        for (int k = 0; k < 2 * D0; k++) acc += t1s[k] * w2[k * NH1 + t];
        h[r * NH1 + t] = fmaxf(acc, 0.f);
    }
}

// ============================================================================
// Kernel 3: GENConv2 + head. 1024 blocks (ONE dst row each) x 256 threads.
// 16 waves/CU (4x the old 256-block layout). Bit-identical per-output math.
// ============================================================================
__global__ __launch_bounds__(256) void genconv2_kernel(
    const float* __restrict__ h, const float* __restrict__ ea,
    const float* __restrict__ we_g, const float* __restrict__ be,
    const float* __restrict__ w1, const float* __restrict__ b1,
    const float* __restrict__ w2, const float* __restrict__ b2,
    const float* __restrict__ fcw, const float* __restrict__ fcb,
    const int* __restrict__ nd, const int* __restrict__ em,
    const int* __restrict__ mask, float* __restrict__ out)
{
    __shared__ int   slots[MAXDEG];
    __shared__ float eatt[MAXDEG * EDIM];
    __shared__ float arow[NH1];
    __shared__ float t2s[2 * NH1];
    __shared__ float h2s[NH1];
    __shared__ int   cnt_s;
    const int t = threadIdx.x;
    const int r = blockIdx.x;
    if (t == 0) cnt_s = 0;
    __syncthreads();

    const int4* nd4 = (const int4*)nd;
    #pragma unroll
    for (int q = 0; q < 8; q++) {
        int idx4 = t + q * 256;
        int4 v = nd4[idx4];
        int n0 = idx4 * 4;
        if (v.x == r) { int p = atomicAdd(&cnt_s, 1); if (p < MAXDEG) slots[p] = n0 + 0; }
        if (v.y == r) { int p = atomicAdd(&cnt_s, 1); if (p < MAXDEG) slots[p] = n0 + 1; }
        if (v.z == r) { int p = atomicAdd(&cnt_s, 1); if (p < MAXDEG) slots[p] = n0 + 2; }
        if (v.w == r) { int p = atomicAdd(&cnt_s, 1); if (p < MAXDEG) slots[p] = n0 + 3; }
    }
    __syncthreads();
    const int cnt = min(cnt_s, MAXDEG);
    if (t == 0) {
        for (int p = 1; p < cnt; p++) {
            int v = slots[p]; int q = p - 1;
            while (q >= 0 && slots[q] > v) { slots[q + 1] = slots[q]; q--; }
            slots[q + 1] = v;
        }
    }
    __syncthreads();
    for (int q = t; q < cnt * EDIM; q += 256)
        eatt[q] = ea[em[slots[q >> 4]] * EDIM + (q & 15)];
    __syncthreads();

    if (t < NH1) {
        const int d = t;
        float wed[EDIM];
        #pragma unroll
        for (int k = 0; k < EDIM; k++) wed[k] = we_g[k * NH1 + d];
        const float bed = be[d];

        float mxv = -FLT_MAX;
        for (int idx = 0; idx < cnt; idx++) {
            int src = slots[idx] >> 3;
            float ep = bed;
            #pragma unroll
            for (int k = 0; k < EDIM; k++) ep += eatt[idx * EDIM + k] * wed[k];
            float m = fmaxf(h[src * NH1 + d] + ep, 0.f) + 1e-7f;
            mxv = fmaxf(mxv, m);
        }
        float den = 0.f, num = 0.f;
        for (int idx = 0; idx < cnt; idx++) {
            int src = slots[idx] >> 3;
            float ep = bed;
            #pragma unroll
            for (int k = 0; k < EDIM; k++) ep += eatt[idx * EDIM + k] * wed[k];
            float m = fmaxf(h[src * NH1 + d] + ep, 0.f) + 1e-7f;
            float w = expf(m - mxv);
            den += w; num += w * m;
        }
        float agg = cnt ? num / (den > 0.f ? den : 1.f) : 0.f;
        arow[d] = agg + h[r * NH1 + d];
    }
    __syncthreads();

    if (t < 2 * NH1) {   // t2: 128 outputs, one thread each
        float acc = b1[t];
        for (int k = 0; k < NH1; k++) acc += arow[k] * w1[k * 2 * NH1 + t];
        t2s[t] = fmaxf(acc, 0.f);
    }
    __syncthreads();
    if (t < NH1) {
        float acc = b2[t];
        for (int k = 0; k < 2 * NH1; k++) acc += t2s[k] * w2[k * NH1 + t];
        h2s[t] = fmaxf(acc, 0.f);
    }
    __syncthreads();
    if (t < NOUT) {
        float acc = fcb[t];
        for (int k = 0; k < NH1; k++) acc += h2s[k] * fcw[k * NOUT + t];
        out[r * NOUT + t] = (mask[r] != 0) ? acc : 0.f;
    }
}

extern "C" void kernel_launch(void* const* d_in, const int* in_sizes, int n_in,
                              void* d_out, int out_size, void* d_ws, size_t ws_size,
                              hipStream_t stream) {
    const float* x      = (const float*)d_in[0];
    const float* ea     = (const float*)d_in[1];
    const float* u      = (const float*)d_in[2];
    const float* mlp_w  = (const float*)d_in[3];
    const float* mlp_b  = (const float*)d_in[4];
    const float* c1_we  = (const float*)d_in[5];
    const float* c1_be  = (const float*)d_in[6];
    const float* c1_w1  = (const float*)d_in[7];
    const float* c1_b1  = (const float*)d_in[8];
    const float* c1_w2  = (const float*)d_in[9];
    const float* c1_b2  = (const float*)d_in[10];
    const float* c2_we  = (const float*)d_in[11];
    const float* c2_be  = (const float*)d_in[12];
    const float* c2_w1  = (const float*)d_in[13];
    const float* c2_b1  = (const float*)d_in[14];
    const float* c2_w2  = (const float*)d_in[15];
    const float* c2_b2  = (const float*)d_in[16];
    const float* fc_w   = (const float*)d_in[17];
    const float* fc_b   = (const float*)d_in[18];
    const int*   ei     = (const int*)d_in[20];
    const int*   mask   = (const int*)d_in[21];

    char* ws = (char*)d_ws;
    int*   em = (int*)(ws + OFF_EM);
    int*   nd = (int*)(ws + OFF_ND);
    float* h  = (float*)(ws + OFF_H);
    float* out = (float*)d_out;

    // 3 dispatches, no memset, no global atomics, no device barriers.
    topk_kernel<<<NN, 512, 0, stream>>>(x, ea, u, mlp_w, mlp_b, ei, c1_w1, nd, em);
    genconv1_kernel<<<NN, 256, 0, stream>>>(x, ea, c1_we, c1_be, c1_w1, c1_b1, c1_w2, c1_b2,
                                            nd, em, h);
    genconv2_kernel<<<NN, 256, 0, stream>>>(h, ea, c2_we, c2_be, c2_w1, c2_b1, c2_w2, c2_b2,
                                            fc_w, fc_b, nd, em, mask, out);
}